// Round 19
// baseline (692.641 us; speedup 1.0000x reference)
//
#include <hip/hip_runtime.h>

#define MAXBUK 512          // buckets of 256 dst-nodes; n=100000 -> 391
#define NREP   8            // cursor/region replicas (spread reservation atomics)
#define PTILE  4096         // edges per k_part3 block
#define CAP_R  1536         // per-(replica,bucket) capacity (mean ~784, +27 sigma)
#define CAPB   10240        // per-bucket csr capacity (mean 8184, +22 sigma)

typedef unsigned short ushort_t;
typedef unsigned int uint_t;
typedef float v2f __attribute__((ext_vector_type(2)));

__device__ inline v2f unpk(uint_t u) {
    v2f r;
    r.x = __uint_as_float(u << 16);
    r.y = __uint_as_float(u & 0xFFFF0000u);
    return r;
}
__device__ inline ushort_t f2bf(float f) {
    union { uint_t u; float f2; } c; c.f2 = f;
    uint_t r = c.u + 0x7FFFu + ((c.u >> 16) & 1u);   // round-to-nearest-even
    return (ushort_t)(r >> 16);
}

// ---------------- partition: staged, replica-reserved, 4096-edge tiles ------
// record: (dst & 255) << 24 | src.  Replica = blockIdx & 7.  bcur[] holds
// per-(replica,bucket) COUNTS (memset-0 init); region base = rb*CAP_R.
__global__ __launch_bounds__(256) void k_part3(
        const int* __restrict__ src, const int* __restrict__ dst,
        int* __restrict__ bcur, uint_t* __restrict__ ebuf, int E) {
    __shared__ int hcnt[MAXBUK];
    __shared__ int lbase[MAXBUK];
    __shared__ int gbase[MAXBUK];
    __shared__ int hcur[MAXBUK];
    __shared__ int psum[256];
    __shared__ uint_t stage[PTILE];
    __shared__ ushort_t sbuk[PTILE];
    int t = threadIdx.x;
    int base = blockIdx.x * PTILE;
    int end = base + PTILE; if (end > E) end = E;
    int cnt = end - base;
    int rep = blockIdx.x & (NREP - 1);
    hcnt[t] = 0; hcnt[t + 256] = 0;
    hcur[t] = 0; hcur[t + 256] = 0;
    __syncthreads();
    // P1: dst -> regs, histogram
    int d[16];
    #pragma unroll
    for (int k = 0; k < 16; k++) {
        int i = base + t + k * 256;
        d[k] = (i < end) ? dst[i] : -1;
        if (d[k] >= 0) atomicAdd(&hcnt[d[k] >> 8], 1);
    }
    __syncthreads();
    // P2: exclusive scan of hcnt (2/thread) + global reservation
    int a0 = hcnt[2 * t], a1 = hcnt[2 * t + 1];
    int ps = a0 + a1;
    psum[t] = ps;
    __syncthreads();
    for (int off = 1; off < 256; off <<= 1) {
        int u = (t >= off) ? psum[t - off] : 0;
        __syncthreads();
        psum[t] += u;
        __syncthreads();
    }
    int ex = psum[t] - ps;
    lbase[2 * t] = ex;
    lbase[2 * t + 1] = ex + a0;
    __syncthreads();
    #pragma unroll
    for (int j = 0; j < 2; j++) {
        int bk = t + j * 256;
        int c = hcnt[bk];
        int rb = (rep << 9) | bk;
        gbase[bk] = c ? (rb * CAP_R + atomicAdd(&bcur[rb], c)) : 0;
    }
    __syncthreads();
    // P3: stage bucket-major in LDS (src read coalesced here)
    #pragma unroll
    for (int k = 0; k < 16; k++) {
        if (d[k] >= 0) {
            int i = base + t + k * 256;
            int bk = d[k] >> 8;
            int p = atomicAdd(&hcur[bk], 1);
            int sp = lbase[bk] + p;
            stage[sp] = ((uint_t)(d[k] & 255) << 24) | (uint_t)src[i];
            sbuk[sp] = (ushort_t)bk;
        }
    }
    __syncthreads();
    // P4: coalesced copy-out (contiguous run per bucket in replica region)
    for (int i = t; i < cnt; i += 256) {
        int bk = sbuk[i];
        ebuf[gbase[bk] + (i - lbase[bk])] = stage[i];
    }
}

// ---------------- per-bucket CSR assembly from 8 replica runs ---------------
__global__ __launch_bounds__(512) void k_csr2(
        const uint_t* __restrict__ ebuf, const int* __restrict__ bcur,
        int* __restrict__ rowptr, int* __restrict__ rowend,
        float* __restrict__ dinv, int* __restrict__ csr, int n) {
    __shared__ uint_t stage[CAPB];
    __shared__ int hist[256];
    __shared__ int scan[256];
    __shared__ int cur[256];
    int b = blockIdx.x;
    int t = threadIdx.x;
    int lo = b * CAPB;
    int nodebase = b << 8;
    if (t < 256) hist[t] = 0;
    // gather replica runs into stage (bcur[rb] = count)
    int tot = 0;
    #pragma unroll
    for (int r = 0; r < NREP; r++) {
        int rb = (r << 9) | b;
        int rbase = rb * CAP_R;
        int c = bcur[rb];
        for (int i = t; i < c; i += 512)
            stage[tot + i] = __builtin_nontemporal_load(&ebuf[rbase + i]);
        tot += c;
    }
    __syncthreads();
    // hist
    for (int i = t; i < tot; i += 512)
        atomicAdd(&hist[stage[i] >> 24], 1);
    __syncthreads();
    int deg = 0;
    if (t < 256) { deg = hist[t]; scan[t] = deg; }
    __syncthreads();
    for (int off = 1; off < 256; off <<= 1) {
        int u = (t < 256 && t >= off) ? scan[t - off] : 0;
        __syncthreads();
        if (t < 256) scan[t] += u;
        __syncthreads();
    }
    if (t < 256) {
        int ex = scan[t] - deg;
        cur[t] = ex;
        int node = nodebase + t;
        if (node < n) {
            rowptr[node] = lo + ex;
            rowend[node] = lo + ex + deg;
            dinv[node] = rsqrtf((float)deg + 1.0f);
        }
    }
    __syncthreads();
    // scatter into this bucket's own csr region
    for (int i = t; i < tot; i += 512) {
        uint_t e = stage[i];
        int p = atomicAdd(&cur[e >> 24], 1);
        csr[lo + p] = (int)(e & 0xFFFFFFu);
    }
}

// ---------------- tiled GEMM (vector-ALU f32, register blocking) ------------
// 128 rows x H cols per block, 512 threads (8 waves): 3 blocks/CU x 8 waves =
// 24 waves/CU (75% occupancy, was 50% at 4x4-wave blocks). Thread tile 4 rows
// x COLV cols. XsT stride 132 floats (=33x16B) keeps XsT[k][tr*4] 16B-aligned
// -> ds_read_b128, conflict-free. W staged per-64-k chunk; kc loop ROLLED
// (#pragma unroll 1; full unroll hit 256 VGPR, min-waves cap spilled) with
// register double-buffer overlapping the FMA phase.
template<int K, int H, bool SCALE, bool BIAS, bool OBF16>
__global__ __launch_bounds__(512) void k_gemm_t(
        const float* __restrict__ X, const float* __restrict__ W,
        const float* __restrict__ bias, const float* __restrict__ dinv,
        void* __restrict__ Yv, int n) {
    constexpr int COLV = H / 16;
    constexpr int WPT = 64 * H / 512;   // W floats per thread per chunk
    __shared__ float Ws[64 * H];
    __shared__ float XsT[64][132];
    int tid = threadIdx.x;
    int tr = tid >> 4;                  // 0..31 (row group of 4)
    int tc = tid & 15;                  // 0..15 (col group of COLV)
    int rowBase = blockIdx.x * 128;
    float acc[4][COLV];
    #pragma unroll
    for (int i = 0; i < 4; i++)
        #pragma unroll
        for (int c = 0; c < COLV; c++) acc[i][c] = 0.f;

    float4 xp[4];
    float wp[WPT];
    // prefetch chunk 0
    #pragma unroll
    for (int j = 0; j < 4; j++) {
        int flat = tid + j * 512;        // 0..2047
        int row = flat >> 4, kv = flat & 15;
        int gr = rowBase + row;
        xp[j] = make_float4(0.f, 0.f, 0.f, 0.f);
        if (gr < n) xp[j] = *reinterpret_cast<const float4*>(X + (size_t)gr * K + kv * 4);
    }
    #pragma unroll
    for (int j = 0; j < WPT; j++) wp[j] = W[tid + j * 512];

    #pragma unroll 1
    for (int kc = 0; kc < K; kc += 64) {
        __syncthreads();                 // LDS free (prev compute done)
        #pragma unroll
        for (int j = 0; j < WPT; j++) Ws[tid + j * 512] = wp[j];
        #pragma unroll
        for (int j = 0; j < 4; j++) {
            int flat = tid + j * 512;
            int row = flat >> 4, kv = flat & 15;
            XsT[kv * 4 + 0][row] = xp[j].x;
            XsT[kv * 4 + 1][row] = xp[j].y;
            XsT[kv * 4 + 2][row] = xp[j].z;
            XsT[kv * 4 + 3][row] = xp[j].w;
        }
        __syncthreads();                 // LDS ready
        if (kc + 64 < K) {               // prefetch next chunk (overlaps FMAs)
            #pragma unroll
            for (int j = 0; j < 4; j++) {
                int flat = tid + j * 512;
                int row = flat >> 4, kv = flat & 15;
                int gr = rowBase + row;
                xp[j] = make_float4(0.f, 0.f, 0.f, 0.f);
                if (gr < n)
                    xp[j] = *reinterpret_cast<const float4*>(X + (size_t)gr * K + kc + 64 + kv * 4);
            }
            #pragma unroll
            for (int j = 0; j < WPT; j++) wp[j] = W[(kc + 64) * H + tid + j * 512];
        }
        #pragma unroll
        for (int k = 0; k < 64; k++) {
            float4 av = *reinterpret_cast<const float4*>(&XsT[k][tr * 4]);
            float avv[4] = {av.x, av.y, av.z, av.w};
            float bvv[COLV];
            if constexpr (COLV == 4) {
                float4 bv = *reinterpret_cast<const float4*>(&Ws[k * H + tc * 4]);
                bvv[0] = bv.x; bvv[1] = bv.y; bvv[2] = bv.z; bvv[3] = bv.w;
            } else {
                float2 bv = *reinterpret_cast<const float2*>(&Ws[k * H + tc * 2]);
                bvv[0] = bv.x; bvv[1] = bv.y;
            }
            #pragma unroll
            for (int i = 0; i < 4; i++)
                #pragma unroll
                for (int c = 0; c < COLV; c++)
                    acc[i][c] = fmaf(avv[i], bvv[c], acc[i][c]);
        }
    }
    #pragma unroll
    for (int i = 0; i < 4; i++) {
        int row = rowBase + tr * 4 + i;
        if (row >= n) continue;
        float s = SCALE ? dinv[row] : 1.f;
        float v[COLV];
        #pragma unroll
        for (int c = 0; c < COLV; c++) {
            float t2 = acc[i][c];
            if (SCALE) t2 *= s;
            if (BIAS)  t2 += bias[tc * COLV + c];
            v[c] = t2;
        }
        if (OBF16) {
            ushort_t* Y = (ushort_t*)Yv;
            ushort4 pk;
            pk.x = f2bf(v[0]); pk.y = f2bf(v[1]);
            pk.z = f2bf(v[2]); pk.w = f2bf(v[3]);
            *reinterpret_cast<ushort4*>(Y + (size_t)row * H + tc * COLV) = pk;
        } else {
            float* Y = (float*)Yv;
            float* yp = Y + (size_t)row * H + tc * COLV;
            if (COLV == 4)      *reinterpret_cast<float4*>(yp) = make_float4(v[0], v[1], v[2], v[3]);
            else                *reinterpret_cast<float2*>(yp) = make_float2(v[0], v[1]);
        }
    }
}

// ---------------- Aggregation: 8 edges per wave-gather (oct layout) ----------
__global__ void k_agg_bf(const int* __restrict__ rowptr, const int* __restrict__ rowend,
                         const int* __restrict__ csr, const uint_t* __restrict__ ytab,
                         const float* __restrict__ dinv, const float* __restrict__ bias,
                         float* __restrict__ out, int n) {
    const char* yb = (const char*)ytab;
    int wave = (int)((blockIdx.x * (size_t)blockDim.x + threadIdx.x) >> 6);
    int lane = threadIdx.x & 63;
    if (wave >= n) return;
    int node = wave;
    int o  = lane >> 3;      // 0..7: edge slot within group of 8
    uint_t fpo = (uint_t)(lane & 7) << 4;   // byte offset of uint4 within row
    v2f a0 = {0.f, 0.f}, a1 = {0.f, 0.f}, a2 = {0.f, 0.f}, a3 = {0.f, 0.f};
    v2f b0 = {0.f, 0.f}, b1 = {0.f, 0.f}, b2 = {0.f, 0.f}, b3 = {0.f, 0.f};
    int s = rowptr[node], e = rowend[node];
    for (int base = s; base < e; base += 64) {
        int rem = e - base; int cnt = rem > 64 ? 64 : rem;
        int idx = (base + lane < e) ? __builtin_nontemporal_load(&csr[base + lane]) : 0;
        int j = 0;
        for (; j + 32 <= cnt; j += 32) {
            uint_t s0 = ((uint_t)__shfl(idx, j + o)      << 7) + fpo;
            uint_t s1 = ((uint_t)__shfl(idx, j + 8 + o)  << 7) + fpo;
            uint_t s2 = ((uint_t)__shfl(idx, j + 16 + o) << 7) + fpo;
            uint_t s3 = ((uint_t)__shfl(idx, j + 24 + o) << 7) + fpo;
            uint4 u0 = *reinterpret_cast<const uint4*>(yb + s0);
            uint4 u1 = *reinterpret_cast<const uint4*>(yb + s1);
            uint4 u2 = *reinterpret_cast<const uint4*>(yb + s2);
            uint4 u3 = *reinterpret_cast<const uint4*>(yb + s3);
            a0 += unpk(u0.x); a1 += unpk(u0.y); a2 += unpk(u0.z); a3 += unpk(u0.w);
            b0 += unpk(u1.x); b1 += unpk(u1.y); b2 += unpk(u1.z); b3 += unpk(u1.w);
            a0 += unpk(u2.x); a1 += unpk(u2.y); a2 += unpk(u2.z); a3 += unpk(u2.w);
            b0 += unpk(u3.x); b1 += unpk(u3.y); b2 += unpk(u3.z); b3 += unpk(u3.w);
        }
        for (; j + 16 <= cnt; j += 16) {
            uint_t s0 = ((uint_t)__shfl(idx, j + o)     << 7) + fpo;
            uint_t s1 = ((uint_t)__shfl(idx, j + 8 + o) << 7) + fpo;
            uint4 u0 = *reinterpret_cast<const uint4*>(yb + s0);
            uint4 u1 = *reinterpret_cast<const uint4*>(yb + s1);
            a0 += unpk(u0.x); a1 += unpk(u0.y); a2 += unpk(u0.z); a3 += unpk(u0.w);
            b0 += unpk(u1.x); b1 += unpk(u1.y); b2 += unpk(u1.z); b3 += unpk(u1.w);
        }
        for (; j + 8 <= cnt; j += 8) {
            uint_t s0 = ((uint_t)__shfl(idx, j + o) << 7) + fpo;
            uint4 u0 = *reinterpret_cast<const uint4*>(yb + s0);
            a0 += unpk(u0.x); a1 += unpk(u0.y); a2 += unpk(u0.z); a3 += unpk(u0.w);
        }
        if (j < cnt) {
            int r2 = cnt - j;                    // 1..7 tail edges
            uint_t s0 = ((uint_t)__shfl(idx, j + (o < r2 ? o : 0)) << 7) + fpo;
            if (o < r2) {
                uint4 u0 = *reinterpret_cast<const uint4*>(yb + s0);
                a0 += unpk(u0.x); a1 += unpk(u0.y); a2 += unpk(u0.z); a3 += unpk(u0.w);
            }
        }
    }
    a0 += b0; a1 += b1; a2 += b2; a3 += b3;
    float f0 = a0.x, f1 = a0.y, f2 = a1.x, f3 = a1.y;
    float f4 = a2.x, f5 = a2.y, f6 = a3.x, f7 = a3.y;
    f0 += __shfl_xor(f0, 8); f0 += __shfl_xor(f0, 16); f0 += __shfl_xor(f0, 32);
    f1 += __shfl_xor(f1, 8); f1 += __shfl_xor(f1, 16); f1 += __shfl_xor(f1, 32);
    f2 += __shfl_xor(f2, 8); f2 += __shfl_xor(f2, 16); f2 += __shfl_xor(f2, 32);
    f3 += __shfl_xor(f3, 8); f3 += __shfl_xor(f3, 16); f3 += __shfl_xor(f3, 32);
    f4 += __shfl_xor(f4, 8); f4 += __shfl_xor(f4, 16); f4 += __shfl_xor(f4, 32);
    f5 += __shfl_xor(f5, 8); f5 += __shfl_xor(f5, 16); f5 += __shfl_xor(f5, 32);
    f6 += __shfl_xor(f6, 8); f6 += __shfl_xor(f6, 16); f6 += __shfl_xor(f6, 32);
    f7 += __shfl_xor(f7, 8); f7 += __shfl_xor(f7, 16); f7 += __shfl_xor(f7, 32);
    if (o == 0) {
        uint_t so = ((uint_t)node << 7) + fpo;   // self-loop
        uint4 su = *reinterpret_cast<const uint4*>(yb + so);
        v2f s0 = unpk(su.x), s1 = unpk(su.y), s2 = unpk(su.z), s3 = unpk(su.w);
        f0 += s0.x; f1 += s0.y; f2 += s1.x; f3 += s1.y;
        f4 += s2.x; f5 += s2.y; f6 += s3.x; f7 += s3.y;
        float di = dinv[node];
        int fp8 = (lane & 7) << 3;
        float4 c0 = *reinterpret_cast<const float4*>(bias + fp8);
        float4 c1 = *reinterpret_cast<const float4*>(bias + fp8 + 4);
        float4 v0, v1;
        v0.x = fmaxf(fmaf(di, f0, c0.x), 0.f);
        v0.y = fmaxf(fmaf(di, f1, c0.y), 0.f);
        v0.z = fmaxf(fmaf(di, f2, c0.z), 0.f);
        v0.w = fmaxf(fmaf(di, f3, c0.w), 0.f);
        v1.x = fmaxf(fmaf(di, f4, c1.x), 0.f);
        v1.y = fmaxf(fmaf(di, f5, c1.y), 0.f);
        v1.z = fmaxf(fmaf(di, f6, c1.z), 0.f);
        v1.w = fmaxf(fmaf(di, f7, c1.w), 0.f);
        float* op = out + (size_t)node * 64 + fp8;
        *reinterpret_cast<float4*>(op) = v0;
        *reinterpret_cast<float4*>(op + 4) = v1;
    }
}

// ---------------- launch ----------------
extern "C" void kernel_launch(void* const* d_in, const int* in_sizes, int n_in,
                              void* d_out, int out_size, void* d_ws, size_t ws_size,
                              hipStream_t stream) {
    const float* x  = (const float*)d_in[0];
    const int*   ei = (const int*)d_in[1];
    const float* W1 = (const float*)d_in[2];
    const float* b1 = (const float*)d_in[3];
    const float* W2 = (const float*)d_in[4];
    const float* b2 = (const float*)d_in[5];
    const float* Wl = (const float*)d_in[6];
    const float* bl = (const float*)d_in[7];
    float* out = (float*)d_out;

    const int n = in_sizes[0] / 128;     // 100000
    const int E = in_sizes[1] / 2;       // 3200000
    const int* src = ei;
    const int* dst = ei + E;
    const int nbuk = (n + 255) >> 8;     // 391

    char* p = (char*)d_ws;
    auto alloc = [&](size_t bytes) { char* r = p; p += (bytes + 255) & ~(size_t)255; return r; };
    float* dinv   = (float*)alloc((size_t)n * 4);
    int*   bcur   = (int*)  alloc(NREP * MAXBUK * 4);
    int*   rowptr = (int*)  alloc((size_t)n * 4);
    int*   rowend = (int*)  alloc((size_t)n * 4);
    int*   csr    = (int*)  alloc((size_t)MAXBUK * CAPB * 4 + 256);
    ushort_t* bufY = (ushort_t*)alloc((size_t)n * 64 * 2);  // bf16 msg table L1
    float* bufA   = (float*)alloc((size_t)n * 64 * 4);      // f32 activations
    ushort_t* bufB = (ushort_t*)alloc((size_t)n * 64 * 2);  // bf16 msg table L2
    (void)ws_size;

    // ebuf (NREP*MAXBUK*CAP_R*4 = 25.2MB) aliases bufA (25.6MB): ebuf is dead
    // after k_csr2, before agg1 writes bufA.
    uint_t* ebuf = (uint_t*)bufA;

    hipMemsetAsync(bcur, 0, NREP * MAXBUK * 4, stream);   // counts, not cursors
    k_part3<<<(E + PTILE - 1) / PTILE, 256, 0, stream>>>(src, dst, bcur, ebuf, E);
    k_csr2<<<nbuk, 512, 0, stream>>>(ebuf, bcur, rowptr, rowend, dinv, csr, n);

    const int GB = (n + 127) / 128;      // 782 blocks, 512 threads
    const int AB = (n + 3) / 4;

    // layer 1: y = dinv ⊙ (x @ W1) [bf16]; h1 = relu(dinv*agg + b1) [f32]
    k_gemm_t<128, 64, true, false, true><<<GB, 512, 0, stream>>>(x, W1, nullptr, dinv, bufY, n);
    k_agg_bf<<<AB, 256, 0, stream>>>(rowptr, rowend, csr, (const uint_t*)bufY, dinv, b1, bufA, n);

    // layer 2
    k_gemm_t<64, 64, true, false, true><<<GB, 512, 0, stream>>>(bufA, W2, nullptr, dinv, bufB, n);
    k_agg_bf<<<AB, 256, 0, stream>>>(rowptr, rowend, csr, (const uint_t*)bufB, dinv, b2, bufA, n);

    // head: out = h2 @ Wl + bl (f32)
    k_gemm_t<64, 32, false, true, false><<<GB, 512, 0, stream>>>(bufA, Wl, bl, nullptr, out, n);
}

// Round 20
// 587.435 us; speedup vs baseline: 1.1791x; 1.1791x over previous
//
#include <hip/hip_runtime.h>

#define MAXBUK 512          // buckets of 256 dst-nodes; n=100000 -> 391
#define NREP   8            // cursor/region replicas (spread reservation atomics)
#define PTILE  4096         // edges per k_part3 block
#define CAP_R  1536         // per-(replica,bucket) capacity (mean ~784, +27 sigma)
#define CAPB   10240        // per-bucket csr capacity (mean 8184, +22 sigma)

typedef unsigned short ushort_t;
typedef unsigned int uint_t;
typedef float v2f __attribute__((ext_vector_type(2)));

__device__ inline v2f unpk(uint_t u) {
    v2f r;
    r.x = __uint_as_float(u << 16);
    r.y = __uint_as_float(u & 0xFFFF0000u);
    return r;
}
__device__ inline ushort_t f2bf(float f) {
    union { uint_t u; float f2; } c; c.f2 = f;
    uint_t r = c.u + 0x7FFFu + ((c.u >> 16) & 1u);   // round-to-nearest-even
    return (ushort_t)(r >> 16);
}

// ---------------- partition: staged, replica-reserved, 4096-edge tiles ------
// record: (dst & 255) << 24 | src.  Replica = blockIdx & 7.  bcur[] holds
// per-(replica,bucket) COUNTS (memset-0 init); region base = rb*CAP_R.
__global__ __launch_bounds__(256) void k_part3(
        const int* __restrict__ src, const int* __restrict__ dst,
        int* __restrict__ bcur, uint_t* __restrict__ ebuf, int E) {
    __shared__ int hcnt[MAXBUK];
    __shared__ int lbase[MAXBUK];
    __shared__ int gbase[MAXBUK];
    __shared__ int hcur[MAXBUK];
    __shared__ int psum[256];
    __shared__ uint_t stage[PTILE];
    __shared__ ushort_t sbuk[PTILE];
    int t = threadIdx.x;
    int base = blockIdx.x * PTILE;
    int end = base + PTILE; if (end > E) end = E;
    int cnt = end - base;
    int rep = blockIdx.x & (NREP - 1);
    hcnt[t] = 0; hcnt[t + 256] = 0;
    hcur[t] = 0; hcur[t + 256] = 0;
    __syncthreads();
    // P1: dst -> regs, histogram
    int d[16];
    #pragma unroll
    for (int k = 0; k < 16; k++) {
        int i = base + t + k * 256;
        d[k] = (i < end) ? dst[i] : -1;
        if (d[k] >= 0) atomicAdd(&hcnt[d[k] >> 8], 1);
    }
    __syncthreads();
    // P2: exclusive scan of hcnt (2/thread) + global reservation
    int a0 = hcnt[2 * t], a1 = hcnt[2 * t + 1];
    int ps = a0 + a1;
    psum[t] = ps;
    __syncthreads();
    for (int off = 1; off < 256; off <<= 1) {
        int u = (t >= off) ? psum[t - off] : 0;
        __syncthreads();
        psum[t] += u;
        __syncthreads();
    }
    int ex = psum[t] - ps;
    lbase[2 * t] = ex;
    lbase[2 * t + 1] = ex + a0;
    __syncthreads();
    #pragma unroll
    for (int j = 0; j < 2; j++) {
        int bk = t + j * 256;
        int c = hcnt[bk];
        int rb = (rep << 9) | bk;
        gbase[bk] = c ? (rb * CAP_R + atomicAdd(&bcur[rb], c)) : 0;
    }
    __syncthreads();
    // P3: stage bucket-major in LDS (src read coalesced here)
    #pragma unroll
    for (int k = 0; k < 16; k++) {
        if (d[k] >= 0) {
            int i = base + t + k * 256;
            int bk = d[k] >> 8;
            int p = atomicAdd(&hcur[bk], 1);
            int sp = lbase[bk] + p;
            stage[sp] = ((uint_t)(d[k] & 255) << 24) | (uint_t)src[i];
            sbuk[sp] = (ushort_t)bk;
        }
    }
    __syncthreads();
    // P4: coalesced copy-out (contiguous run per bucket in replica region)
    for (int i = t; i < cnt; i += 256) {
        int bk = sbuk[i];
        ebuf[gbase[bk] + (i - lbase[bk])] = stage[i];
    }
}

// ---------------- per-bucket CSR assembly from 8 replica runs ---------------
__global__ __launch_bounds__(512) void k_csr2(
        const uint_t* __restrict__ ebuf, const int* __restrict__ bcur,
        int* __restrict__ rowptr, int* __restrict__ rowend,
        float* __restrict__ dinv, int* __restrict__ csr, int n) {
    __shared__ uint_t stage[CAPB];
    __shared__ int hist[256];
    __shared__ int scan[256];
    __shared__ int cur[256];
    int b = blockIdx.x;
    int t = threadIdx.x;
    int lo = b * CAPB;
    int nodebase = b << 8;
    if (t < 256) hist[t] = 0;
    // gather replica runs into stage (bcur[rb] = count)
    int tot = 0;
    #pragma unroll
    for (int r = 0; r < NREP; r++) {
        int rb = (r << 9) | b;
        int rbase = rb * CAP_R;
        int c = bcur[rb];
        for (int i = t; i < c; i += 512)
            stage[tot + i] = __builtin_nontemporal_load(&ebuf[rbase + i]);
        tot += c;
    }
    __syncthreads();
    // hist
    for (int i = t; i < tot; i += 512)
        atomicAdd(&hist[stage[i] >> 24], 1);
    __syncthreads();
    int deg = 0;
    if (t < 256) { deg = hist[t]; scan[t] = deg; }
    __syncthreads();
    for (int off = 1; off < 256; off <<= 1) {
        int u = (t < 256 && t >= off) ? scan[t - off] : 0;
        __syncthreads();
        if (t < 256) scan[t] += u;
        __syncthreads();
    }
    if (t < 256) {
        int ex = scan[t] - deg;
        cur[t] = ex;
        int node = nodebase + t;
        if (node < n) {
            rowptr[node] = lo + ex;
            rowend[node] = lo + ex + deg;
            dinv[node] = rsqrtf((float)deg + 1.0f);
        }
    }
    __syncthreads();
    // scatter into this bucket's own csr region
    for (int i = t; i < tot; i += 512) {
        uint_t e = stage[i];
        int p = atomicAdd(&cur[e >> 24], 1);
        csr[lo + p] = (int)(e & 0xFFFFFFu);
    }
}

// ---------------- tiled GEMM (vector-ALU f32, register blocking) ------------
// 128 rows x H cols per block, 256 threads (4 waves): thread = 8 rows x COLV
// cols -> per k-step 3x ds_read_b128 feed 32 FMAs (VALU-bound inner loop; r18's
// 4-row tile was 2 reads/16 FMAs, LDS-issue bound). No launch_bounds VGPR cap
// (r16/r19: caps -> scratch spill). XsT stride 132 floats (33x16B) keeps
// XsT[k][tr*8] 16B-aligned. kc loop ROLLED with register double-buffer.
template<int K, int H, bool SCALE, bool BIAS, bool OBF16>
__global__ __launch_bounds__(256) void k_gemm_t(
        const float* __restrict__ X, const float* __restrict__ W,
        const float* __restrict__ bias, const float* __restrict__ dinv,
        void* __restrict__ Yv, int n) {
    constexpr int COLV = H / 16;
    constexpr int WPT = 64 * H / 256;   // W floats per thread per chunk
    __shared__ float Ws[64 * H];
    __shared__ float XsT[64][132];
    int tid = threadIdx.x;
    int tr = tid >> 4;                  // 0..15 (row group of 8)
    int tc = tid & 15;                  // 0..15 (col group of COLV)
    int rowBase = blockIdx.x * 128;
    float acc[8][COLV];
    #pragma unroll
    for (int i = 0; i < 8; i++)
        #pragma unroll
        for (int c = 0; c < COLV; c++) acc[i][c] = 0.f;

    float4 xp[8];
    float wp[WPT];
    // prefetch chunk 0
    #pragma unroll
    for (int j = 0; j < 8; j++) {
        int flat = tid + j * 256;        // 0..2047
        int row = flat >> 4, kv = flat & 15;
        int gr = rowBase + row;
        xp[j] = make_float4(0.f, 0.f, 0.f, 0.f);
        if (gr < n) xp[j] = *reinterpret_cast<const float4*>(X + (size_t)gr * K + kv * 4);
    }
    #pragma unroll
    for (int j = 0; j < WPT; j++) wp[j] = W[tid + j * 256];

    #pragma unroll 1
    for (int kc = 0; kc < K; kc += 64) {
        __syncthreads();                 // LDS free (prev compute done)
        #pragma unroll
        for (int j = 0; j < WPT; j++) Ws[tid + j * 256] = wp[j];
        #pragma unroll
        for (int j = 0; j < 8; j++) {
            int flat = tid + j * 256;
            int row = flat >> 4, kv = flat & 15;
            XsT[kv * 4 + 0][row] = xp[j].x;
            XsT[kv * 4 + 1][row] = xp[j].y;
            XsT[kv * 4 + 2][row] = xp[j].z;
            XsT[kv * 4 + 3][row] = xp[j].w;
        }
        __syncthreads();                 // LDS ready
        if (kc + 64 < K) {               // prefetch next chunk (overlaps FMAs)
            #pragma unroll
            for (int j = 0; j < 8; j++) {
                int flat = tid + j * 256;
                int row = flat >> 4, kv = flat & 15;
                int gr = rowBase + row;
                xp[j] = make_float4(0.f, 0.f, 0.f, 0.f);
                if (gr < n)
                    xp[j] = *reinterpret_cast<const float4*>(X + (size_t)gr * K + kc + 64 + kv * 4);
            }
            #pragma unroll
            for (int j = 0; j < WPT; j++) wp[j] = W[(kc + 64) * H + tid + j * 256];
        }
        #pragma unroll
        for (int k = 0; k < 64; k++) {
            float4 av0 = *reinterpret_cast<const float4*>(&XsT[k][tr * 8]);
            float4 av1 = *reinterpret_cast<const float4*>(&XsT[k][tr * 8 + 4]);
            float avv[8] = {av0.x, av0.y, av0.z, av0.w, av1.x, av1.y, av1.z, av1.w};
            float bvv[COLV];
            if constexpr (COLV == 4) {
                float4 bv = *reinterpret_cast<const float4*>(&Ws[k * H + tc * 4]);
                bvv[0] = bv.x; bvv[1] = bv.y; bvv[2] = bv.z; bvv[3] = bv.w;
            } else {
                float2 bv = *reinterpret_cast<const float2*>(&Ws[k * H + tc * 2]);
                bvv[0] = bv.x; bvv[1] = bv.y;
            }
            #pragma unroll
            for (int i = 0; i < 8; i++)
                #pragma unroll
                for (int c = 0; c < COLV; c++)
                    acc[i][c] = fmaf(avv[i], bvv[c], acc[i][c]);
        }
    }
    #pragma unroll
    for (int i = 0; i < 8; i++) {
        int row = rowBase + tr * 8 + i;
        if (row >= n) continue;
        float s = SCALE ? dinv[row] : 1.f;
        float v[COLV];
        #pragma unroll
        for (int c = 0; c < COLV; c++) {
            float t2 = acc[i][c];
            if (SCALE) t2 *= s;
            if (BIAS)  t2 += bias[tc * COLV + c];
            v[c] = t2;
        }
        if (OBF16) {
            ushort_t* Y = (ushort_t*)Yv;
            ushort4 pk;
            pk.x = f2bf(v[0]); pk.y = f2bf(v[1]);
            pk.z = f2bf(v[2]); pk.w = f2bf(v[3]);
            *reinterpret_cast<ushort4*>(Y + (size_t)row * H + tc * COLV) = pk;
        } else {
            float* Y = (float*)Yv;
            float* yp = Y + (size_t)row * H + tc * COLV;
            if (COLV == 4)      *reinterpret_cast<float4*>(yp) = make_float4(v[0], v[1], v[2], v[3]);
            else                *reinterpret_cast<float2*>(yp) = make_float2(v[0], v[1]);
        }
    }
}

// ---------------- Aggregation: 8 edges per wave-gather (oct layout) ----------
__global__ void k_agg_bf(const int* __restrict__ rowptr, const int* __restrict__ rowend,
                         const int* __restrict__ csr, const uint_t* __restrict__ ytab,
                         const float* __restrict__ dinv, const float* __restrict__ bias,
                         float* __restrict__ out, int n) {
    const char* yb = (const char*)ytab;
    int wave = (int)((blockIdx.x * (size_t)blockDim.x + threadIdx.x) >> 6);
    int lane = threadIdx.x & 63;
    if (wave >= n) return;
    int node = wave;
    int o  = lane >> 3;      // 0..7: edge slot within group of 8
    uint_t fpo = (uint_t)(lane & 7) << 4;   // byte offset of uint4 within row
    v2f a0 = {0.f, 0.f}, a1 = {0.f, 0.f}, a2 = {0.f, 0.f}, a3 = {0.f, 0.f};
    v2f b0 = {0.f, 0.f}, b1 = {0.f, 0.f}, b2 = {0.f, 0.f}, b3 = {0.f, 0.f};
    int s = rowptr[node], e = rowend[node];
    for (int base = s; base < e; base += 64) {
        int rem = e - base; int cnt = rem > 64 ? 64 : rem;
        int idx = (base + lane < e) ? __builtin_nontemporal_load(&csr[base + lane]) : 0;
        int j = 0;
        for (; j + 32 <= cnt; j += 32) {
            uint_t s0 = ((uint_t)__shfl(idx, j + o)      << 7) + fpo;
            uint_t s1 = ((uint_t)__shfl(idx, j + 8 + o)  << 7) + fpo;
            uint_t s2 = ((uint_t)__shfl(idx, j + 16 + o) << 7) + fpo;
            uint_t s3 = ((uint_t)__shfl(idx, j + 24 + o) << 7) + fpo;
            uint4 u0 = *reinterpret_cast<const uint4*>(yb + s0);
            uint4 u1 = *reinterpret_cast<const uint4*>(yb + s1);
            uint4 u2 = *reinterpret_cast<const uint4*>(yb + s2);
            uint4 u3 = *reinterpret_cast<const uint4*>(yb + s3);
            a0 += unpk(u0.x); a1 += unpk(u0.y); a2 += unpk(u0.z); a3 += unpk(u0.w);
            b0 += unpk(u1.x); b1 += unpk(u1.y); b2 += unpk(u1.z); b3 += unpk(u1.w);
            a0 += unpk(u2.x); a1 += unpk(u2.y); a2 += unpk(u2.z); a3 += unpk(u2.w);
            b0 += unpk(u3.x); b1 += unpk(u3.y); b2 += unpk(u3.z); b3 += unpk(u3.w);
        }
        for (; j + 16 <= cnt; j += 16) {
            uint_t s0 = ((uint_t)__shfl(idx, j + o)     << 7) + fpo;
            uint_t s1 = ((uint_t)__shfl(idx, j + 8 + o) << 7) + fpo;
            uint4 u0 = *reinterpret_cast<const uint4*>(yb + s0);
            uint4 u1 = *reinterpret_cast<const uint4*>(yb + s1);
            a0 += unpk(u0.x); a1 += unpk(u0.y); a2 += unpk(u0.z); a3 += unpk(u0.w);
            b0 += unpk(u1.x); b1 += unpk(u1.y); b2 += unpk(u1.z); b3 += unpk(u1.w);
        }
        for (; j + 8 <= cnt; j += 8) {
            uint_t s0 = ((uint_t)__shfl(idx, j + o) << 7) + fpo;
            uint4 u0 = *reinterpret_cast<const uint4*>(yb + s0);
            a0 += unpk(u0.x); a1 += unpk(u0.y); a2 += unpk(u0.z); a3 += unpk(u0.w);
        }
        if (j < cnt) {
            int r2 = cnt - j;                    // 1..7 tail edges
            uint_t s0 = ((uint_t)__shfl(idx, j + (o < r2 ? o : 0)) << 7) + fpo;
            if (o < r2) {
                uint4 u0 = *reinterpret_cast<const uint4*>(yb + s0);
                a0 += unpk(u0.x); a1 += unpk(u0.y); a2 += unpk(u0.z); a3 += unpk(u0.w);
            }
        }
    }
    a0 += b0; a1 += b1; a2 += b2; a3 += b3;
    float f0 = a0.x, f1 = a0.y, f2 = a1.x, f3 = a1.y;
    float f4 = a2.x, f5 = a2.y, f6 = a3.x, f7 = a3.y;
    f0 += __shfl_xor(f0, 8); f0 += __shfl_xor(f0, 16); f0 += __shfl_xor(f0, 32);
    f1 += __shfl_xor(f1, 8); f1 += __shfl_xor(f1, 16); f1 += __shfl_xor(f1, 32);
    f2 += __shfl_xor(f2, 8); f2 += __shfl_xor(f2, 16); f2 += __shfl_xor(f2, 32);
    f3 += __shfl_xor(f3, 8); f3 += __shfl_xor(f3, 16); f3 += __shfl_xor(f3, 32);
    f4 += __shfl_xor(f4, 8); f4 += __shfl_xor(f4, 16); f4 += __shfl_xor(f4, 32);
    f5 += __shfl_xor(f5, 8); f5 += __shfl_xor(f5, 16); f5 += __shfl_xor(f5, 32);
    f6 += __shfl_xor(f6, 8); f6 += __shfl_xor(f6, 16); f6 += __shfl_xor(f6, 32);
    f7 += __shfl_xor(f7, 8); f7 += __shfl_xor(f7, 16); f7 += __shfl_xor(f7, 32);
    if (o == 0) {
        uint_t so = ((uint_t)node << 7) + fpo;   // self-loop
        uint4 su = *reinterpret_cast<const uint4*>(yb + so);
        v2f s0 = unpk(su.x), s1 = unpk(su.y), s2 = unpk(su.z), s3 = unpk(su.w);
        f0 += s0.x; f1 += s0.y; f2 += s1.x; f3 += s1.y;
        f4 += s2.x; f5 += s2.y; f6 += s3.x; f7 += s3.y;
        float di = dinv[node];
        int fp8 = (lane & 7) << 3;
        float4 c0 = *reinterpret_cast<const float4*>(bias + fp8);
        float4 c1 = *reinterpret_cast<const float4*>(bias + fp8 + 4);
        float4 v0, v1;
        v0.x = fmaxf(fmaf(di, f0, c0.x), 0.f);
        v0.y = fmaxf(fmaf(di, f1, c0.y), 0.f);
        v0.z = fmaxf(fmaf(di, f2, c0.z), 0.f);
        v0.w = fmaxf(fmaf(di, f3, c0.w), 0.f);
        v1.x = fmaxf(fmaf(di, f4, c1.x), 0.f);
        v1.y = fmaxf(fmaf(di, f5, c1.y), 0.f);
        v1.z = fmaxf(fmaf(di, f6, c1.z), 0.f);
        v1.w = fmaxf(fmaf(di, f7, c1.w), 0.f);
        float* op = out + (size_t)node * 64 + fp8;
        *reinterpret_cast<float4*>(op) = v0;
        *reinterpret_cast<float4*>(op + 4) = v1;
    }
}

// ---------------- launch ----------------
extern "C" void kernel_launch(void* const* d_in, const int* in_sizes, int n_in,
                              void* d_out, int out_size, void* d_ws, size_t ws_size,
                              hipStream_t stream) {
    const float* x  = (const float*)d_in[0];
    const int*   ei = (const int*)d_in[1];
    const float* W1 = (const float*)d_in[2];
    const float* b1 = (const float*)d_in[3];
    const float* W2 = (const float*)d_in[4];
    const float* b2 = (const float*)d_in[5];
    const float* Wl = (const float*)d_in[6];
    const float* bl = (const float*)d_in[7];
    float* out = (float*)d_out;

    const int n = in_sizes[0] / 128;     // 100000
    const int E = in_sizes[1] / 2;       // 3200000
    const int* src = ei;
    const int* dst = ei + E;
    const int nbuk = (n + 255) >> 8;     // 391

    char* p = (char*)d_ws;
    auto alloc = [&](size_t bytes) { char* r = p; p += (bytes + 255) & ~(size_t)255; return r; };
    float* dinv   = (float*)alloc((size_t)n * 4);
    int*   bcur   = (int*)  alloc(NREP * MAXBUK * 4);
    int*   rowptr = (int*)  alloc((size_t)n * 4);
    int*   rowend = (int*)  alloc((size_t)n * 4);
    int*   csr    = (int*)  alloc((size_t)MAXBUK * CAPB * 4 + 256);
    ushort_t* bufY = (ushort_t*)alloc((size_t)n * 64 * 2);  // bf16 msg table L1
    float* bufA   = (float*)alloc((size_t)n * 64 * 4);      // f32 activations
    ushort_t* bufB = (ushort_t*)alloc((size_t)n * 64 * 2);  // bf16 msg table L2
    (void)ws_size;

    // ebuf (NREP*MAXBUK*CAP_R*4 = 25.2MB) aliases bufA (25.6MB): ebuf is dead
    // after k_csr2, before agg1 writes bufA.
    uint_t* ebuf = (uint_t*)bufA;

    hipMemsetAsync(bcur, 0, NREP * MAXBUK * 4, stream);   // counts, not cursors
    k_part3<<<(E + PTILE - 1) / PTILE, 256, 0, stream>>>(src, dst, bcur, ebuf, E);
    k_csr2<<<nbuk, 512, 0, stream>>>(ebuf, bcur, rowptr, rowend, dinv, csr, n);

    const int GB = (n + 127) / 128;      // 782 blocks, 256 threads
    const int AB = (n + 3) / 4;

    // layer 1: y = dinv ⊙ (x @ W1) [bf16]; h1 = relu(dinv*agg + b1) [f32]
    k_gemm_t<128, 64, true, false, true><<<GB, 256, 0, stream>>>(x, W1, nullptr, dinv, bufY, n);
    k_agg_bf<<<AB, 256, 0, stream>>>(rowptr, rowend, csr, (const uint_t*)bufY, dinv, b1, bufA, n);

    // layer 2
    k_gemm_t<64, 64, true, false, true><<<GB, 256, 0, stream>>>(bufA, W2, nullptr, dinv, bufB, n);
    k_agg_bf<<<AB, 256, 0, stream>>>(rowptr, rowend, csr, (const uint_t*)bufB, dinv, b2, bufA, n);

    // head: out = h2 @ Wl + bl (f32)
    k_gemm_t<64, 32, false, true, false><<<GB, 256, 0, stream>>>(bufA, Wl, bl, nullptr, out, n);
}

// Round 21
// 219.177 us; speedup vs baseline: 3.1602x; 2.6802x over previous
//
#include <hip/hip_runtime.h>

#define MAXBUK 512          // buckets of 256 dst-nodes; n=100000 -> 391
#define NREP   8            // cursor/region replicas (spread reservation atomics)
#define PTILE  4096         // edges per k_part3 block
#define CAP_R  1536         // per-(replica,bucket) capacity (mean ~784, +27 sigma)
#define CAPB   10240        // per-bucket csr capacity (mean 8184, +22 sigma)

typedef unsigned short ushort_t;
typedef unsigned int uint_t;
typedef float v2f __attribute__((ext_vector_type(2)));

__device__ inline v2f unpk(uint_t u) {
    v2f r;
    r.x = __uint_as_float(u << 16);
    r.y = __uint_as_float(u & 0xFFFF0000u);
    return r;
}
__device__ inline ushort_t f2bf(float f) {
    union { uint_t u; float f2; } c; c.f2 = f;
    uint_t r = c.u + 0x7FFFu + ((c.u >> 16) & 1u);   // round-to-nearest-even
    return (ushort_t)(r >> 16);
}

// ---------------- partition: staged, replica-reserved, 4096-edge tiles ------
// record: (dst & 255) << 24 | src.  Replica = blockIdx & 7.  bcur[] holds
// per-(replica,bucket) COUNTS (memset-0 init); region base = rb*CAP_R.
__global__ __launch_bounds__(256) void k_part3(
        const int* __restrict__ src, const int* __restrict__ dst,
        int* __restrict__ bcur, uint_t* __restrict__ ebuf, int E) {
    __shared__ int hcnt[MAXBUK];
    __shared__ int lbase[MAXBUK];
    __shared__ int gbase[MAXBUK];
    __shared__ int hcur[MAXBUK];
    __shared__ int psum[256];
    __shared__ uint_t stage[PTILE];
    __shared__ ushort_t sbuk[PTILE];
    int t = threadIdx.x;
    int base = blockIdx.x * PTILE;
    int end = base + PTILE; if (end > E) end = E;
    int cnt = end - base;
    int rep = blockIdx.x & (NREP - 1);
    hcnt[t] = 0; hcnt[t + 256] = 0;
    hcur[t] = 0; hcur[t + 256] = 0;
    __syncthreads();
    // P1: dst -> regs, histogram
    int d[16];
    #pragma unroll
    for (int k = 0; k < 16; k++) {
        int i = base + t + k * 256;
        d[k] = (i < end) ? dst[i] : -1;
        if (d[k] >= 0) atomicAdd(&hcnt[d[k] >> 8], 1);
    }
    __syncthreads();
    // P2: exclusive scan of hcnt (2/thread) + global reservation
    int a0 = hcnt[2 * t], a1 = hcnt[2 * t + 1];
    int ps = a0 + a1;
    psum[t] = ps;
    __syncthreads();
    for (int off = 1; off < 256; off <<= 1) {
        int u = (t >= off) ? psum[t - off] : 0;
        __syncthreads();
        psum[t] += u;
        __syncthreads();
    }
    int ex = psum[t] - ps;
    lbase[2 * t] = ex;
    lbase[2 * t + 1] = ex + a0;
    __syncthreads();
    #pragma unroll
    for (int j = 0; j < 2; j++) {
        int bk = t + j * 256;
        int c = hcnt[bk];
        int rb = (rep << 9) | bk;
        gbase[bk] = c ? (rb * CAP_R + atomicAdd(&bcur[rb], c)) : 0;
    }
    __syncthreads();
    // P3: stage bucket-major in LDS (src read coalesced here)
    #pragma unroll
    for (int k = 0; k < 16; k++) {
        if (d[k] >= 0) {
            int i = base + t + k * 256;
            int bk = d[k] >> 8;
            int p = atomicAdd(&hcur[bk], 1);
            int sp = lbase[bk] + p;
            stage[sp] = ((uint_t)(d[k] & 255) << 24) | (uint_t)src[i];
            sbuk[sp] = (ushort_t)bk;
        }
    }
    __syncthreads();
    // P4: coalesced copy-out (contiguous run per bucket in replica region)
    for (int i = t; i < cnt; i += 256) {
        int bk = sbuk[i];
        ebuf[gbase[bk] + (i - lbase[bk])] = stage[i];
    }
}

// ---------------- per-bucket CSR assembly from 8 replica runs ---------------
__global__ __launch_bounds__(512) void k_csr2(
        const uint_t* __restrict__ ebuf, const int* __restrict__ bcur,
        int* __restrict__ rowptr, int* __restrict__ rowend,
        float* __restrict__ dinv, int* __restrict__ csr, int n) {
    __shared__ uint_t stage[CAPB];
    __shared__ int hist[256];
    __shared__ int scan[256];
    __shared__ int cur[256];
    int b = blockIdx.x;
    int t = threadIdx.x;
    int lo = b * CAPB;
    int nodebase = b << 8;
    if (t < 256) hist[t] = 0;
    // gather replica runs into stage (bcur[rb] = count)
    int tot = 0;
    #pragma unroll
    for (int r = 0; r < NREP; r++) {
        int rb = (r << 9) | b;
        int rbase = rb * CAP_R;
        int c = bcur[rb];
        for (int i = t; i < c; i += 512)
            stage[tot + i] = __builtin_nontemporal_load(&ebuf[rbase + i]);
        tot += c;
    }
    __syncthreads();
    // hist
    for (int i = t; i < tot; i += 512)
        atomicAdd(&hist[stage[i] >> 24], 1);
    __syncthreads();
    int deg = 0;
    if (t < 256) { deg = hist[t]; scan[t] = deg; }
    __syncthreads();
    for (int off = 1; off < 256; off <<= 1) {
        int u = (t < 256 && t >= off) ? scan[t - off] : 0;
        __syncthreads();
        if (t < 256) scan[t] += u;
        __syncthreads();
    }
    if (t < 256) {
        int ex = scan[t] - deg;
        cur[t] = ex;
        int node = nodebase + t;
        if (node < n) {
            rowptr[node] = lo + ex;
            rowend[node] = lo + ex + deg;
            dinv[node] = rsqrtf((float)deg + 1.0f);
        }
    }
    __syncthreads();
    // scatter into this bucket's own csr region
    for (int i = t; i < tot; i += 512) {
        uint_t e = stage[i];
        int p = atomicAdd(&cur[e >> 24], 1);
        csr[lo + p] = (int)(e & 0xFFFFFFu);
    }
}

// ---------------- tiled GEMM (vector-ALU f32, register blocking) ------------
// r18 structure (64 rows x H cols per block, 256 threads, 4-row x COLV thread
// tile, XsT stride 68 = 17x16B -> b128 reads) with k-chunk HALVED to 32:
// LDS 16.9KB -> 8 blocks/CU x 4 waves = 32 waves/CU (was 16). Per-thread
// state SHRINKS (xp 2x float4, wp <=8) -> no spill risk (r16/r19/r20: caps or
// bigger tiles all spilled). kc loop ROLLED with register double-buffer.
template<int K, int H, bool SCALE, bool BIAS, bool OBF16>
__global__ __launch_bounds__(256) void k_gemm_t(
        const float* __restrict__ X, const float* __restrict__ W,
        const float* __restrict__ bias, const float* __restrict__ dinv,
        void* __restrict__ Yv, int n) {
    constexpr int COLV = H / 16;
    constexpr int KCH = 32;             // k-chunk
    constexpr int WPT = KCH * H / 256;  // W floats per thread per chunk
    __shared__ float Ws[KCH * H];
    __shared__ float XsT[KCH][68];
    int tid = threadIdx.x;
    int tr = tid >> 4;                  // 0..15 (row group of 4)
    int tc = tid & 15;                  // 0..15 (col group of COLV)
    int rowBase = blockIdx.x * 64;
    float acc[4][COLV];
    #pragma unroll
    for (int i = 0; i < 4; i++)
        #pragma unroll
        for (int c = 0; c < COLV; c++) acc[i][c] = 0.f;

    float4 xp[2];
    float wp[WPT];
    // prefetch chunk 0: 64 rows x 32 cols = 512 float4, 2 per thread
    #pragma unroll
    for (int j = 0; j < 2; j++) {
        int flat = tid + j * 256;        // 0..511
        int row = flat >> 3, kv = flat & 7;
        int gr = rowBase + row;
        xp[j] = make_float4(0.f, 0.f, 0.f, 0.f);
        if (gr < n) xp[j] = *reinterpret_cast<const float4*>(X + (size_t)gr * K + kv * 4);
    }
    #pragma unroll
    for (int j = 0; j < WPT; j++) wp[j] = W[tid + j * 256];

    #pragma unroll 1
    for (int kc = 0; kc < K; kc += KCH) {
        __syncthreads();                 // LDS free (prev compute done)
        #pragma unroll
        for (int j = 0; j < WPT; j++) Ws[tid + j * 256] = wp[j];
        #pragma unroll
        for (int j = 0; j < 2; j++) {
            int flat = tid + j * 256;
            int row = flat >> 3, kv = flat & 7;
            XsT[kv * 4 + 0][row] = xp[j].x;
            XsT[kv * 4 + 1][row] = xp[j].y;
            XsT[kv * 4 + 2][row] = xp[j].z;
            XsT[kv * 4 + 3][row] = xp[j].w;
        }
        __syncthreads();                 // LDS ready
        if (kc + KCH < K) {              // prefetch next chunk (overlaps FMAs)
            #pragma unroll
            for (int j = 0; j < 2; j++) {
                int flat = tid + j * 256;
                int row = flat >> 3, kv = flat & 7;
                int gr = rowBase + row;
                xp[j] = make_float4(0.f, 0.f, 0.f, 0.f);
                if (gr < n)
                    xp[j] = *reinterpret_cast<const float4*>(X + (size_t)gr * K + kc + KCH + kv * 4);
            }
            #pragma unroll
            for (int j = 0; j < WPT; j++) wp[j] = W[(kc + KCH) * H + tid + j * 256];
        }
        #pragma unroll
        for (int k = 0; k < KCH; k++) {
            float4 av = *reinterpret_cast<const float4*>(&XsT[k][tr * 4]);
            float avv[4] = {av.x, av.y, av.z, av.w};
            float bvv[COLV];
            if constexpr (COLV == 4) {
                float4 bv = *reinterpret_cast<const float4*>(&Ws[k * H + tc * 4]);
                bvv[0] = bv.x; bvv[1] = bv.y; bvv[2] = bv.z; bvv[3] = bv.w;
            } else {
                float2 bv = *reinterpret_cast<const float2*>(&Ws[k * H + tc * 2]);
                bvv[0] = bv.x; bvv[1] = bv.y;
            }
            #pragma unroll
            for (int i = 0; i < 4; i++)
                #pragma unroll
                for (int c = 0; c < COLV; c++)
                    acc[i][c] = fmaf(avv[i], bvv[c], acc[i][c]);
        }
    }
    #pragma unroll
    for (int i = 0; i < 4; i++) {
        int row = rowBase + tr * 4 + i;
        if (row >= n) continue;
        float s = SCALE ? dinv[row] : 1.f;
        float v[COLV];
        #pragma unroll
        for (int c = 0; c < COLV; c++) {
            float t2 = acc[i][c];
            if (SCALE) t2 *= s;
            if (BIAS)  t2 += bias[tc * COLV + c];
            v[c] = t2;
        }
        if (OBF16) {
            ushort_t* Y = (ushort_t*)Yv;
            ushort4 pk;
            pk.x = f2bf(v[0]); pk.y = f2bf(v[1]);
            pk.z = f2bf(v[2]); pk.w = f2bf(v[3]);
            *reinterpret_cast<ushort4*>(Y + (size_t)row * H + tc * COLV) = pk;
        } else {
            float* Y = (float*)Yv;
            float* yp = Y + (size_t)row * H + tc * COLV;
            if (COLV == 4)      *reinterpret_cast<float4*>(yp) = make_float4(v[0], v[1], v[2], v[3]);
            else                *reinterpret_cast<float2*>(yp) = make_float2(v[0], v[1]);
        }
    }
}

// ---------------- Aggregation: 8 edges per wave-gather (oct layout) ----------
__global__ void k_agg_bf(const int* __restrict__ rowptr, const int* __restrict__ rowend,
                         const int* __restrict__ csr, const uint_t* __restrict__ ytab,
                         const float* __restrict__ dinv, const float* __restrict__ bias,
                         float* __restrict__ out, int n) {
    const char* yb = (const char*)ytab;
    int wave = (int)((blockIdx.x * (size_t)blockDim.x + threadIdx.x) >> 6);
    int lane = threadIdx.x & 63;
    if (wave >= n) return;
    int node = wave;
    int o  = lane >> 3;      // 0..7: edge slot within group of 8
    uint_t fpo = (uint_t)(lane & 7) << 4;   // byte offset of uint4 within row
    v2f a0 = {0.f, 0.f}, a1 = {0.f, 0.f}, a2 = {0.f, 0.f}, a3 = {0.f, 0.f};
    v2f b0 = {0.f, 0.f}, b1 = {0.f, 0.f}, b2 = {0.f, 0.f}, b3 = {0.f, 0.f};
    int s = rowptr[node], e = rowend[node];
    for (int base = s; base < e; base += 64) {
        int rem = e - base; int cnt = rem > 64 ? 64 : rem;
        int idx = (base + lane < e) ? __builtin_nontemporal_load(&csr[base + lane]) : 0;
        int j = 0;
        for (; j + 32 <= cnt; j += 32) {
            uint_t s0 = ((uint_t)__shfl(idx, j + o)      << 7) + fpo;
            uint_t s1 = ((uint_t)__shfl(idx, j + 8 + o)  << 7) + fpo;
            uint_t s2 = ((uint_t)__shfl(idx, j + 16 + o) << 7) + fpo;
            uint_t s3 = ((uint_t)__shfl(idx, j + 24 + o) << 7) + fpo;
            uint4 u0 = *reinterpret_cast<const uint4*>(yb + s0);
            uint4 u1 = *reinterpret_cast<const uint4*>(yb + s1);
            uint4 u2 = *reinterpret_cast<const uint4*>(yb + s2);
            uint4 u3 = *reinterpret_cast<const uint4*>(yb + s3);
            a0 += unpk(u0.x); a1 += unpk(u0.y); a2 += unpk(u0.z); a3 += unpk(u0.w);
            b0 += unpk(u1.x); b1 += unpk(u1.y); b2 += unpk(u1.z); b3 += unpk(u1.w);
            a0 += unpk(u2.x); a1 += unpk(u2.y); a2 += unpk(u2.z); a3 += unpk(u2.w);
            b0 += unpk(u3.x); b1 += unpk(u3.y); b2 += unpk(u3.z); b3 += unpk(u3.w);
        }
        for (; j + 16 <= cnt; j += 16) {
            uint_t s0 = ((uint_t)__shfl(idx, j + o)     << 7) + fpo;
            uint_t s1 = ((uint_t)__shfl(idx, j + 8 + o) << 7) + fpo;
            uint4 u0 = *reinterpret_cast<const uint4*>(yb + s0);
            uint4 u1 = *reinterpret_cast<const uint4*>(yb + s1);
            a0 += unpk(u0.x); a1 += unpk(u0.y); a2 += unpk(u0.z); a3 += unpk(u0.w);
            b0 += unpk(u1.x); b1 += unpk(u1.y); b2 += unpk(u1.z); b3 += unpk(u1.w);
        }
        for (; j + 8 <= cnt; j += 8) {
            uint_t s0 = ((uint_t)__shfl(idx, j + o) << 7) + fpo;
            uint4 u0 = *reinterpret_cast<const uint4*>(yb + s0);
            a0 += unpk(u0.x); a1 += unpk(u0.y); a2 += unpk(u0.z); a3 += unpk(u0.w);
        }
        if (j < cnt) {
            int r2 = cnt - j;                    // 1..7 tail edges
            uint_t s0 = ((uint_t)__shfl(idx, j + (o < r2 ? o : 0)) << 7) + fpo;
            if (o < r2) {
                uint4 u0 = *reinterpret_cast<const uint4*>(yb + s0);
                a0 += unpk(u0.x); a1 += unpk(u0.y); a2 += unpk(u0.z); a3 += unpk(u0.w);
            }
        }
    }
    a0 += b0; a1 += b1; a2 += b2; a3 += b3;
    float f0 = a0.x, f1 = a0.y, f2 = a1.x, f3 = a1.y;
    float f4 = a2.x, f5 = a2.y, f6 = a3.x, f7 = a3.y;
    f0 += __shfl_xor(f0, 8); f0 += __shfl_xor(f0, 16); f0 += __shfl_xor(f0, 32);
    f1 += __shfl_xor(f1, 8); f1 += __shfl_xor(f1, 16); f1 += __shfl_xor(f1, 32);
    f2 += __shfl_xor(f2, 8); f2 += __shfl_xor(f2, 16); f2 += __shfl_xor(f2, 32);
    f3 += __shfl_xor(f3, 8); f3 += __shfl_xor(f3, 16); f3 += __shfl_xor(f3, 32);
    f4 += __shfl_xor(f4, 8); f4 += __shfl_xor(f4, 16); f4 += __shfl_xor(f4, 32);
    f5 += __shfl_xor(f5, 8); f5 += __shfl_xor(f5, 16); f5 += __shfl_xor(f5, 32);
    f6 += __shfl_xor(f6, 8); f6 += __shfl_xor(f6, 16); f6 += __shfl_xor(f6, 32);
    f7 += __shfl_xor(f7, 8); f7 += __shfl_xor(f7, 16); f7 += __shfl_xor(f7, 32);
    if (o == 0) {
        uint_t so = ((uint_t)node << 7) + fpo;   // self-loop
        uint4 su = *reinterpret_cast<const uint4*>(yb + so);
        v2f s0 = unpk(su.x), s1 = unpk(su.y), s2 = unpk(su.z), s3 = unpk(su.w);
        f0 += s0.x; f1 += s0.y; f2 += s1.x; f3 += s1.y;
        f4 += s2.x; f5 += s2.y; f6 += s3.x; f7 += s3.y;
        float di = dinv[node];
        int fp8 = (lane & 7) << 3;
        float4 c0 = *reinterpret_cast<const float4*>(bias + fp8);
        float4 c1 = *reinterpret_cast<const float4*>(bias + fp8 + 4);
        float4 v0, v1;
        v0.x = fmaxf(fmaf(di, f0, c0.x), 0.f);
        v0.y = fmaxf(fmaf(di, f1, c0.y), 0.f);
        v0.z = fmaxf(fmaf(di, f2, c0.z), 0.f);
        v0.w = fmaxf(fmaf(di, f3, c0.w), 0.f);
        v1.x = fmaxf(fmaf(di, f4, c1.x), 0.f);
        v1.y = fmaxf(fmaf(di, f5, c1.y), 0.f);
        v1.z = fmaxf(fmaf(di, f6, c1.z), 0.f);
        v1.w = fmaxf(fmaf(di, f7, c1.w), 0.f);
        float* op = out + (size_t)node * 64 + fp8;
        *reinterpret_cast<float4*>(op) = v0;
        *reinterpret_cast<float4*>(op + 4) = v1;
    }
}

// ---------------- launch ----------------
extern "C" void kernel_launch(void* const* d_in, const int* in_sizes, int n_in,
                              void* d_out, int out_size, void* d_ws, size_t ws_size,
                              hipStream_t stream) {
    const float* x  = (const float*)d_in[0];
    const int*   ei = (const int*)d_in[1];
    const float* W1 = (const float*)d_in[2];
    const float* b1 = (const float*)d_in[3];
    const float* W2 = (const float*)d_in[4];
    const float* b2 = (const float*)d_in[5];
    const float* Wl = (const float*)d_in[6];
    const float* bl = (const float*)d_in[7];
    float* out = (float*)d_out;

    const int n = in_sizes[0] / 128;     // 100000
    const int E = in_sizes[1] / 2;       // 3200000
    const int* src = ei;
    const int* dst = ei + E;
    const int nbuk = (n + 255) >> 8;     // 391

    char* p = (char*)d_ws;
    auto alloc = [&](size_t bytes) { char* r = p; p += (bytes + 255) & ~(size_t)255; return r; };
    float* dinv   = (float*)alloc((size_t)n * 4);
    int*   bcur   = (int*)  alloc(NREP * MAXBUK * 4);
    int*   rowptr = (int*)  alloc((size_t)n * 4);
    int*   rowend = (int*)  alloc((size_t)n * 4);
    int*   csr    = (int*)  alloc((size_t)MAXBUK * CAPB * 4 + 256);
    ushort_t* bufY = (ushort_t*)alloc((size_t)n * 64 * 2);  // bf16 msg table L1
    float* bufA   = (float*)alloc((size_t)n * 64 * 4);      // f32 activations
    ushort_t* bufB = (ushort_t*)alloc((size_t)n * 64 * 2);  // bf16 msg table L2
    (void)ws_size;

    // ebuf (NREP*MAXBUK*CAP_R*4 = 25.2MB) aliases bufA (25.6MB): ebuf is dead
    // after k_csr2, before agg1 writes bufA.
    uint_t* ebuf = (uint_t*)bufA;

    hipMemsetAsync(bcur, 0, NREP * MAXBUK * 4, stream);   // counts, not cursors
    k_part3<<<(E + PTILE - 1) / PTILE, 256, 0, stream>>>(src, dst, bcur, ebuf, E);
    k_csr2<<<nbuk, 512, 0, stream>>>(ebuf, bcur, rowptr, rowend, dinv, csr, n);

    const int GB = (n + 63) / 64;        // 1563 blocks, 256 threads
    const int AB = (n + 3) / 4;

    // layer 1: y = dinv ⊙ (x @ W1) [bf16]; h1 = relu(dinv*agg + b1) [f32]
    k_gemm_t<128, 64, true, false, true><<<GB, 256, 0, stream>>>(x, W1, nullptr, dinv, bufY, n);
    k_agg_bf<<<AB, 256, 0, stream>>>(rowptr, rowend, csr, (const uint_t*)bufY, dinv, b1, bufA, n);

    // layer 2
    k_gemm_t<64, 64, true, false, true><<<GB, 256, 0, stream>>>(bufA, W2, nullptr, dinv, bufB, n);
    k_agg_bf<<<AB, 256, 0, stream>>>(rowptr, rowend, csr, (const uint_t*)bufB, dinv, b2, bufA, n);

    // head: out = h2 @ Wl + bl (f32)
    k_gemm_t<64, 32, false, true, false><<<GB, 256, 0, stream>>>(bufA, Wl, bl, nullptr, out, n);
}

// Round 22
// 216.993 us; speedup vs baseline: 3.1920x; 1.0101x over previous
//
#include <hip/hip_runtime.h>

#define MAXBUK 512          // buckets of 256 dst-nodes; n=100000 -> 391
#define NREP   8            // cursor/region replicas (spread reservation atomics)
#define PTILE  8192         // edges per k_part3 block (512 threads)
#define CAP_R  1536         // per-(replica,bucket) capacity (mean ~784, +27 sigma)
#define CAPB   10240        // per-bucket csr capacity (mean 8184, +22 sigma)

typedef unsigned short ushort_t;
typedef unsigned int uint_t;
typedef float v2f __attribute__((ext_vector_type(2)));

__device__ inline v2f unpk(uint_t u) {
    v2f r;
    r.x = __uint_as_float(u << 16);
    r.y = __uint_as_float(u & 0xFFFF0000u);
    return r;
}
__device__ inline ushort_t f2bf(float f) {
    union { uint_t u; float f2; } c; c.f2 = f;
    uint_t r = c.u + 0x7FFFu + ((c.u >> 16) & 1u);   // round-to-nearest-even
    return (ushort_t)(r >> 16);
}

// ---------------- partition: staged, replica-reserved, 8192-edge tiles ------
// record: (dst & 255) << 24 | src.  Replica = blockIdx & 7.  bcur[] holds
// per-(replica,bucket) COUNTS (memset-0 init); region base = rb*CAP_R.
// 512 threads: one bucket per thread for scan/reservation (half the atomics
// and blocks of the 4096/256 variant).
__global__ __launch_bounds__(512) void k_part3(
        const int* __restrict__ src, const int* __restrict__ dst,
        int* __restrict__ bcur, uint_t* __restrict__ ebuf, int E) {
    __shared__ int hcnt[MAXBUK];
    __shared__ int lbase[MAXBUK];
    __shared__ int gbase[MAXBUK];
    __shared__ int hcur[MAXBUK];
    __shared__ int psum[MAXBUK];
    __shared__ uint_t stage[PTILE];
    __shared__ ushort_t sbuk[PTILE];
    int t = threadIdx.x;
    int base = blockIdx.x * PTILE;
    int end = base + PTILE; if (end > E) end = E;
    int cnt = end - base;
    int rep = blockIdx.x & (NREP - 1);
    hcnt[t] = 0; hcur[t] = 0;
    __syncthreads();
    // P1: dst -> regs, histogram
    int d[16];
    #pragma unroll
    for (int k = 0; k < 16; k++) {
        int i = base + t + k * 512;
        d[k] = (i < end) ? dst[i] : -1;
        if (d[k] >= 0) atomicAdd(&hcnt[d[k] >> 8], 1);
    }
    __syncthreads();
    // P2: exclusive scan over 512 buckets (1/thread) + global reservation
    int cb = hcnt[t];
    psum[t] = cb;
    __syncthreads();
    for (int off = 1; off < MAXBUK; off <<= 1) {
        int u = (t >= off) ? psum[t - off] : 0;
        __syncthreads();
        psum[t] += u;
        __syncthreads();
    }
    lbase[t] = psum[t] - cb;
    {
        int rb = (rep << 9) | t;
        gbase[t] = cb ? (rb * CAP_R + atomicAdd(&bcur[rb], cb)) : 0;
    }
    __syncthreads();
    // P3: stage bucket-major in LDS (src read coalesced here)
    #pragma unroll
    for (int k = 0; k < 16; k++) {
        if (d[k] >= 0) {
            int i = base + t + k * 512;
            int bk = d[k] >> 8;
            int p = atomicAdd(&hcur[bk], 1);
            int sp = lbase[bk] + p;
            stage[sp] = ((uint_t)(d[k] & 255) << 24) | (uint_t)src[i];
            sbuk[sp] = (ushort_t)bk;
        }
    }
    __syncthreads();
    // P4: coalesced copy-out (contiguous run per bucket in replica region)
    for (int i = t; i < cnt; i += 512) {
        int bk = sbuk[i];
        ebuf[gbase[bk] + (i - lbase[bk])] = stage[i];
    }
}

// ---------------- per-bucket CSR assembly from 8 replica runs ---------------
__global__ __launch_bounds__(512) void k_csr2(
        const uint_t* __restrict__ ebuf, const int* __restrict__ bcur,
        int* __restrict__ rowptr, int* __restrict__ rowend,
        float* __restrict__ dinv, int* __restrict__ csr, int n) {
    __shared__ uint_t stage[CAPB];
    __shared__ int hist[256];
    __shared__ int scan[256];
    __shared__ int cur[256];
    int b = blockIdx.x;
    int t = threadIdx.x;
    int lo = b * CAPB;
    int nodebase = b << 8;
    if (t < 256) hist[t] = 0;
    // gather replica runs into stage (bcur[rb] = count)
    int tot = 0;
    #pragma unroll
    for (int r = 0; r < NREP; r++) {
        int rb = (r << 9) | b;
        int rbase = rb * CAP_R;
        int c = bcur[rb];
        for (int i = t; i < c; i += 512)
            stage[tot + i] = __builtin_nontemporal_load(&ebuf[rbase + i]);
        tot += c;
    }
    __syncthreads();
    // hist
    for (int i = t; i < tot; i += 512)
        atomicAdd(&hist[stage[i] >> 24], 1);
    __syncthreads();
    int deg = 0;
    if (t < 256) { deg = hist[t]; scan[t] = deg; }
    __syncthreads();
    for (int off = 1; off < 256; off <<= 1) {
        int u = (t < 256 && t >= off) ? scan[t - off] : 0;
        __syncthreads();
        if (t < 256) scan[t] += u;
        __syncthreads();
    }
    if (t < 256) {
        int ex = scan[t] - deg;
        cur[t] = ex;
        int node = nodebase + t;
        if (node < n) {
            rowptr[node] = lo + ex;
            rowend[node] = lo + ex + deg;
            dinv[node] = rsqrtf((float)deg + 1.0f);
        }
    }
    __syncthreads();
    // scatter into this bucket's own csr region
    for (int i = t; i < tot; i += 512) {
        uint_t e = stage[i];
        int p = atomicAdd(&cur[e >> 24], 1);
        csr[lo + p] = (int)(e & 0xFFFFFFu);
    }
}

// ---------------- tiled GEMM (vector-ALU f32, register blocking) ------------
// 64 rows x H cols per block, 256 threads, 4-row x COLV thread tile, XsT
// stride 68 (17x16B) -> b128 reads; k-chunk 32 -> LDS 16.9KB -> 8 blocks/CU
// x 4 waves = 32 waves/CU. Per-thread state small (xp 2x float4, wp <=8):
// no spill (r16/r19/r20: caps or bigger tiles all spilled). kc loop ROLLED
// with register double-buffer.
template<int K, int H, bool SCALE, bool BIAS, bool OBF16>
__global__ __launch_bounds__(256) void k_gemm_t(
        const float* __restrict__ X, const float* __restrict__ W,
        const float* __restrict__ bias, const float* __restrict__ dinv,
        void* __restrict__ Yv, int n) {
    constexpr int COLV = H / 16;
    constexpr int KCH = 32;             // k-chunk
    constexpr int WPT = KCH * H / 256;  // W floats per thread per chunk
    __shared__ float Ws[KCH * H];
    __shared__ float XsT[KCH][68];
    int tid = threadIdx.x;
    int tr = tid >> 4;                  // 0..15 (row group of 4)
    int tc = tid & 15;                  // 0..15 (col group of COLV)
    int rowBase = blockIdx.x * 64;
    float acc[4][COLV];
    #pragma unroll
    for (int i = 0; i < 4; i++)
        #pragma unroll
        for (int c = 0; c < COLV; c++) acc[i][c] = 0.f;

    float4 xp[2];
    float wp[WPT];
    // prefetch chunk 0: 64 rows x 32 cols = 512 float4, 2 per thread
    #pragma unroll
    for (int j = 0; j < 2; j++) {
        int flat = tid + j * 256;        // 0..511
        int row = flat >> 3, kv = flat & 7;
        int gr = rowBase + row;
        xp[j] = make_float4(0.f, 0.f, 0.f, 0.f);
        if (gr < n) xp[j] = *reinterpret_cast<const float4*>(X + (size_t)gr * K + kv * 4);
    }
    #pragma unroll
    for (int j = 0; j < WPT; j++) wp[j] = W[tid + j * 256];

    #pragma unroll 1
    for (int kc = 0; kc < K; kc += KCH) {
        __syncthreads();                 // LDS free (prev compute done)
        #pragma unroll
        for (int j = 0; j < WPT; j++) Ws[tid + j * 256] = wp[j];
        #pragma unroll
        for (int j = 0; j < 2; j++) {
            int flat = tid + j * 256;
            int row = flat >> 3, kv = flat & 7;
            XsT[kv * 4 + 0][row] = xp[j].x;
            XsT[kv * 4 + 1][row] = xp[j].y;
            XsT[kv * 4 + 2][row] = xp[j].z;
            XsT[kv * 4 + 3][row] = xp[j].w;
        }
        __syncthreads();                 // LDS ready
        if (kc + KCH < K) {              // prefetch next chunk (overlaps FMAs)
            #pragma unroll
            for (int j = 0; j < 2; j++) {
                int flat = tid + j * 256;
                int row = flat >> 3, kv = flat & 7;
                int gr = rowBase + row;
                xp[j] = make_float4(0.f, 0.f, 0.f, 0.f);
                if (gr < n)
                    xp[j] = *reinterpret_cast<const float4*>(X + (size_t)gr * K + kc + KCH + kv * 4);
            }
            #pragma unroll
            for (int j = 0; j < WPT; j++) wp[j] = W[(kc + KCH) * H + tid + j * 256];
        }
        #pragma unroll
        for (int k = 0; k < KCH; k++) {
            float4 av = *reinterpret_cast<const float4*>(&XsT[k][tr * 4]);
            float avv[4] = {av.x, av.y, av.z, av.w};
            float bvv[COLV];
            if constexpr (COLV == 4) {
                float4 bv = *reinterpret_cast<const float4*>(&Ws[k * H + tc * 4]);
                bvv[0] = bv.x; bvv[1] = bv.y; bvv[2] = bv.z; bvv[3] = bv.w;
            } else {
                float2 bv = *reinterpret_cast<const float2*>(&Ws[k * H + tc * 2]);
                bvv[0] = bv.x; bvv[1] = bv.y;
            }
            #pragma unroll
            for (int i = 0; i < 4; i++)
                #pragma unroll
                for (int c = 0; c < COLV; c++)
                    acc[i][c] = fmaf(avv[i], bvv[c], acc[i][c]);
        }
    }
    #pragma unroll
    for (int i = 0; i < 4; i++) {
        int row = rowBase + tr * 4 + i;
        if (row >= n) continue;
        float s = SCALE ? dinv[row] : 1.f;
        float v[COLV];
        #pragma unroll
        for (int c = 0; c < COLV; c++) {
            float t2 = acc[i][c];
            if (SCALE) t2 *= s;
            if (BIAS)  t2 += bias[tc * COLV + c];
            v[c] = t2;
        }
        if (OBF16) {
            ushort_t* Y = (ushort_t*)Yv;
            ushort4 pk;
            pk.x = f2bf(v[0]); pk.y = f2bf(v[1]);
            pk.z = f2bf(v[2]); pk.w = f2bf(v[3]);
            *reinterpret_cast<ushort4*>(Y + (size_t)row * H + tc * COLV) = pk;
        } else {
            float* Y = (float*)Yv;
            float* yp = Y + (size_t)row * H + tc * COLV;
            if (COLV == 4)      *reinterpret_cast<float4*>(yp) = make_float4(v[0], v[1], v[2], v[3]);
            else                *reinterpret_cast<float2*>(yp) = make_float2(v[0], v[1]);
        }
    }
}

// ---------------- Aggregation: 8 edges per wave-gather (oct layout) ----------
__global__ void k_agg_bf(const int* __restrict__ rowptr, const int* __restrict__ rowend,
                         const int* __restrict__ csr, const uint_t* __restrict__ ytab,
                         const float* __restrict__ dinv, const float* __restrict__ bias,
                         float* __restrict__ out, int n) {
    const char* yb = (const char*)ytab;
    int wave = (int)((blockIdx.x * (size_t)blockDim.x + threadIdx.x) >> 6);
    int lane = threadIdx.x & 63;
    if (wave >= n) return;
    int node = wave;
    int o  = lane >> 3;      // 0..7: edge slot within group of 8
    uint_t fpo = (uint_t)(lane & 7) << 4;   // byte offset of uint4 within row
    v2f a0 = {0.f, 0.f}, a1 = {0.f, 0.f}, a2 = {0.f, 0.f}, a3 = {0.f, 0.f};
    v2f b0 = {0.f, 0.f}, b1 = {0.f, 0.f}, b2 = {0.f, 0.f}, b3 = {0.f, 0.f};
    int s = rowptr[node], e = rowend[node];
    for (int base = s; base < e; base += 64) {
        int rem = e - base; int cnt = rem > 64 ? 64 : rem;
        int idx = (base + lane < e) ? __builtin_nontemporal_load(&csr[base + lane]) : 0;
        int j = 0;
        for (; j + 32 <= cnt; j += 32) {
            uint_t s0 = ((uint_t)__shfl(idx, j + o)      << 7) + fpo;
            uint_t s1 = ((uint_t)__shfl(idx, j + 8 + o)  << 7) + fpo;
            uint_t s2 = ((uint_t)__shfl(idx, j + 16 + o) << 7) + fpo;
            uint_t s3 = ((uint_t)__shfl(idx, j + 24 + o) << 7) + fpo;
            uint4 u0 = *reinterpret_cast<const uint4*>(yb + s0);
            uint4 u1 = *reinterpret_cast<const uint4*>(yb + s1);
            uint4 u2 = *reinterpret_cast<const uint4*>(yb + s2);
            uint4 u3 = *reinterpret_cast<const uint4*>(yb + s3);
            a0 += unpk(u0.x); a1 += unpk(u0.y); a2 += unpk(u0.z); a3 += unpk(u0.w);
            b0 += unpk(u1.x); b1 += unpk(u1.y); b2 += unpk(u1.z); b3 += unpk(u1.w);
            a0 += unpk(u2.x); a1 += unpk(u2.y); a2 += unpk(u2.z); a3 += unpk(u2.w);
            b0 += unpk(u3.x); b1 += unpk(u3.y); b2 += unpk(u3.z); b3 += unpk(u3.w);
        }
        for (; j + 16 <= cnt; j += 16) {
            uint_t s0 = ((uint_t)__shfl(idx, j + o)     << 7) + fpo;
            uint_t s1 = ((uint_t)__shfl(idx, j + 8 + o) << 7) + fpo;
            uint4 u0 = *reinterpret_cast<const uint4*>(yb + s0);
            uint4 u1 = *reinterpret_cast<const uint4*>(yb + s1);
            a0 += unpk(u0.x); a1 += unpk(u0.y); a2 += unpk(u0.z); a3 += unpk(u0.w);
            b0 += unpk(u1.x); b1 += unpk(u1.y); b2 += unpk(u1.z); b3 += unpk(u1.w);
        }
        for (; j + 8 <= cnt; j += 8) {
            uint_t s0 = ((uint_t)__shfl(idx, j + o) << 7) + fpo;
            uint4 u0 = *reinterpret_cast<const uint4*>(yb + s0);
            a0 += unpk(u0.x); a1 += unpk(u0.y); a2 += unpk(u0.z); a3 += unpk(u0.w);
        }
        if (j < cnt) {
            int r2 = cnt - j;                    // 1..7 tail edges
            uint_t s0 = ((uint_t)__shfl(idx, j + (o < r2 ? o : 0)) << 7) + fpo;
            if (o < r2) {
                uint4 u0 = *reinterpret_cast<const uint4*>(yb + s0);
                a0 += unpk(u0.x); a1 += unpk(u0.y); a2 += unpk(u0.z); a3 += unpk(u0.w);
            }
        }
    }
    a0 += b0; a1 += b1; a2 += b2; a3 += b3;
    float f0 = a0.x, f1 = a0.y, f2 = a1.x, f3 = a1.y;
    float f4 = a2.x, f5 = a2.y, f6 = a3.x, f7 = a3.y;
    f0 += __shfl_xor(f0, 8); f0 += __shfl_xor(f0, 16); f0 += __shfl_xor(f0, 32);
    f1 += __shfl_xor(f1, 8); f1 += __shfl_xor(f1, 16); f1 += __shfl_xor(f1, 32);
    f2 += __shfl_xor(f2, 8); f2 += __shfl_xor(f2, 16); f2 += __shfl_xor(f2, 32);
    f3 += __shfl_xor(f3, 8); f3 += __shfl_xor(f3, 16); f3 += __shfl_xor(f3, 32);
    f4 += __shfl_xor(f4, 8); f4 += __shfl_xor(f4, 16); f4 += __shfl_xor(f4, 32);
    f5 += __shfl_xor(f5, 8); f5 += __shfl_xor(f5, 16); f5 += __shfl_xor(f5, 32);
    f6 += __shfl_xor(f6, 8); f6 += __shfl_xor(f6, 16); f6 += __shfl_xor(f6, 32);
    f7 += __shfl_xor(f7, 8); f7 += __shfl_xor(f7, 16); f7 += __shfl_xor(f7, 32);
    if (o == 0) {
        uint_t so = ((uint_t)node << 7) + fpo;   // self-loop
        uint4 su = *reinterpret_cast<const uint4*>(yb + so);
        v2f s0 = unpk(su.x), s1 = unpk(su.y), s2 = unpk(su.z), s3 = unpk(su.w);
        f0 += s0.x; f1 += s0.y; f2 += s1.x; f3 += s1.y;
        f4 += s2.x; f5 += s2.y; f6 += s3.x; f7 += s3.y;
        float di = dinv[node];
        int fp8 = (lane & 7) << 3;
        float4 c0 = *reinterpret_cast<const float4*>(bias + fp8);
        float4 c1 = *reinterpret_cast<const float4*>(bias + fp8 + 4);
        float4 v0, v1;
        v0.x = fmaxf(fmaf(di, f0, c0.x), 0.f);
        v0.y = fmaxf(fmaf(di, f1, c0.y), 0.f);
        v0.z = fmaxf(fmaf(di, f2, c0.z), 0.f);
        v0.w = fmaxf(fmaf(di, f3, c0.w), 0.f);
        v1.x = fmaxf(fmaf(di, f4, c1.x), 0.f);
        v1.y = fmaxf(fmaf(di, f5, c1.y), 0.f);
        v1.z = fmaxf(fmaf(di, f6, c1.z), 0.f);
        v1.w = fmaxf(fmaf(di, f7, c1.w), 0.f);
        float* op = out + (size_t)node * 64 + fp8;
        *reinterpret_cast<float4*>(op) = v0;
        *reinterpret_cast<float4*>(op + 4) = v1;
    }
}

// ---------------- launch ----------------
extern "C" void kernel_launch(void* const* d_in, const int* in_sizes, int n_in,
                              void* d_out, int out_size, void* d_ws, size_t ws_size,
                              hipStream_t stream) {
    const float* x  = (const float*)d_in[0];
    const int*   ei = (const int*)d_in[1];
    const float* W1 = (const float*)d_in[2];
    const float* b1 = (const float*)d_in[3];
    const float* W2 = (const float*)d_in[4];
    const float* b2 = (const float*)d_in[5];
    const float* Wl = (const float*)d_in[6];
    const float* bl = (const float*)d_in[7];
    float* out = (float*)d_out;

    const int n = in_sizes[0] / 128;     // 100000
    const int E = in_sizes[1] / 2;       // 3200000
    const int* src = ei;
    const int* dst = ei + E;
    const int nbuk = (n + 255) >> 8;     // 391

    char* p = (char*)d_ws;
    auto alloc = [&](size_t bytes) { char* r = p; p += (bytes + 255) & ~(size_t)255; return r; };
    float* dinv   = (float*)alloc((size_t)n * 4);
    int*   bcur   = (int*)  alloc(NREP * MAXBUK * 4);
    int*   rowptr = (int*)  alloc((size_t)n * 4);
    int*   rowend = (int*)  alloc((size_t)n * 4);
    int*   csr    = (int*)  alloc((size_t)MAXBUK * CAPB * 4 + 256);
    ushort_t* bufY = (ushort_t*)alloc((size_t)n * 64 * 2);  // bf16 msg table L1
    float* bufA   = (float*)alloc((size_t)n * 64 * 4);      // f32 activations
    ushort_t* bufB = (ushort_t*)alloc((size_t)n * 64 * 2);  // bf16 msg table L2
    (void)ws_size;

    // ebuf (NREP*MAXBUK*CAP_R*4 = 25.2MB) aliases bufA (25.6MB): ebuf is dead
    // after k_csr2, before agg1 writes bufA.
    uint_t* ebuf = (uint_t*)bufA;

    hipMemsetAsync(bcur, 0, NREP * MAXBUK * 4, stream);   // counts, not cursors
    k_part3<<<(E + PTILE - 1) / PTILE, 512, 0, stream>>>(src, dst, bcur, ebuf, E);
    k_csr2<<<nbuk, 512, 0, stream>>>(ebuf, bcur, rowptr, rowend, dinv, csr, n);

    const int GB = (n + 63) / 64;        // 1563 blocks, 256 threads
    const int AB = (n + 3) / 4;

    // layer 1: y = dinv ⊙ (x @ W1) [bf16]; h1 = relu(dinv*agg + b1) [f32]
    k_gemm_t<128, 64, true, false, true><<<GB, 256, 0, stream>>>(x, W1, nullptr, dinv, bufY, n);
    k_agg_bf<<<AB, 256, 0, stream>>>(rowptr, rowend, csr, (const uint_t*)bufY, dinv, b1, bufA, n);

    // layer 2
    k_gemm_t<64, 64, true, false, true><<<GB, 256, 0, stream>>>(bufA, W2, nullptr, dinv, bufB, n);
    k_agg_bf<<<AB, 256, 0, stream>>>(rowptr, rowend, csr, (const uint_t*)bufB, dinv, b2, bufA, n);

    // head: out = h2 @ Wl + bl (f32)
    k_gemm_t<64, 32, false, true, false><<<GB, 256, 0, stream>>>(bufA, Wl, bl, nullptr, out, n);
}

// Round 23
// 216.389 us; speedup vs baseline: 3.2009x; 1.0028x over previous
//
#include <hip/hip_runtime.h>

#define MAXBUK 512          // buckets of 256 dst-nodes; n=100000 -> 391
#define NREP   8            // cursor/region replicas (spread reservation atomics)
#define PTILE  8192         // edges per k_part3 block (512 threads)
#define CAP_R  1536         // per-(replica,bucket) capacity (mean ~784, +27 sigma)
#define CAPB   10240        // per-bucket csr capacity (mean 8184, +22 sigma)

typedef unsigned short ushort_t;
typedef unsigned int uint_t;
typedef float v2f __attribute__((ext_vector_type(2)));

__device__ inline v2f unpk(uint_t u) {
    v2f r;
    r.x = __uint_as_float(u << 16);
    r.y = __uint_as_float(u & 0xFFFF0000u);
    return r;
}
__device__ inline ushort_t f2bf(float f) {
    union { uint_t u; float f2; } c; c.f2 = f;
    uint_t r = c.u + 0x7FFFu + ((c.u >> 16) & 1u);   // round-to-nearest-even
    return (ushort_t)(r >> 16);
}

// ---------------- partition: staged, replica-reserved, 8192-edge tiles ------
// record: (dst & 255) << 24 | src.  Replica = blockIdx & 7.  bcur[] holds
// per-(replica,bucket) COUNTS (memset-0 init); region base = rb*CAP_R.
__global__ __launch_bounds__(512) void k_part3(
        const int* __restrict__ src, const int* __restrict__ dst,
        int* __restrict__ bcur, uint_t* __restrict__ ebuf, int E) {
    __shared__ int hcnt[MAXBUK];
    __shared__ int lbase[MAXBUK];
    __shared__ int gbase[MAXBUK];
    __shared__ int hcur[MAXBUK];
    __shared__ int psum[MAXBUK];
    __shared__ uint_t stage[PTILE];
    __shared__ ushort_t sbuk[PTILE];
    int t = threadIdx.x;
    int base = blockIdx.x * PTILE;
    int end = base + PTILE; if (end > E) end = E;
    int cnt = end - base;
    int rep = blockIdx.x & (NREP - 1);
    hcnt[t] = 0; hcur[t] = 0;
    __syncthreads();
    // P1: dst -> regs, histogram
    int d[16];
    #pragma unroll
    for (int k = 0; k < 16; k++) {
        int i = base + t + k * 512;
        d[k] = (i < end) ? dst[i] : -1;
        if (d[k] >= 0) atomicAdd(&hcnt[d[k] >> 8], 1);
    }
    __syncthreads();
    // P2: exclusive scan over 512 buckets (1/thread) + global reservation
    int cb = hcnt[t];
    psum[t] = cb;
    __syncthreads();
    for (int off = 1; off < MAXBUK; off <<= 1) {
        int u = (t >= off) ? psum[t - off] : 0;
        __syncthreads();
        psum[t] += u;
        __syncthreads();
    }
    lbase[t] = psum[t] - cb;
    {
        int rb = (rep << 9) | t;
        gbase[t] = cb ? (rb * CAP_R + atomicAdd(&bcur[rb], cb)) : 0;
    }
    __syncthreads();
    // P3: stage bucket-major in LDS (src read coalesced here)
    #pragma unroll
    for (int k = 0; k < 16; k++) {
        if (d[k] >= 0) {
            int i = base + t + k * 512;
            int bk = d[k] >> 8;
            int p = atomicAdd(&hcur[bk], 1);
            int sp = lbase[bk] + p;
            stage[sp] = ((uint_t)(d[k] & 255) << 24) | (uint_t)src[i];
            sbuk[sp] = (ushort_t)bk;
        }
    }
    __syncthreads();
    // P4: coalesced copy-out (contiguous run per bucket in replica region)
    for (int i = t; i < cnt; i += 512) {
        int bk = sbuk[i];
        ebuf[gbase[bk] + (i - lbase[bk])] = stage[i];
    }
}

// ---------------- per-bucket CSR assembly from 8 replica runs ---------------
// Counts preloaded + register prefix offsets -> the 8 run-copy loops issue
// independently (was a serial tot+=c chain, 8 dependent latency hops); hist
// fused into the copy (atomicAdd from register, one fewer barrier + LDS pass).
__global__ __launch_bounds__(512) void k_csr2(
        const uint_t* __restrict__ ebuf, const int* __restrict__ bcur,
        int* __restrict__ rowptr, int* __restrict__ rowend,
        float* __restrict__ dinv, int* __restrict__ csr, int n) {
    __shared__ uint_t stage[CAPB];
    __shared__ int hist[256];
    __shared__ int scan[256];
    __shared__ int cur[256];
    int b = blockIdx.x;
    int t = threadIdx.x;
    int lo = b * CAPB;
    int nodebase = b << 8;
    if (t < 256) hist[t] = 0;
    __syncthreads();
    // preload counts + prefix offsets (uniform -> scalar)
    int cnts[NREP], offs[NREP];
    int tot = 0;
    #pragma unroll
    for (int r = 0; r < NREP; r++) {
        cnts[r] = bcur[(r << 9) | b];
        offs[r] = tot;
        tot += cnts[r];
    }
    // fused gather + histogram (runs independent, loads overlap)
    #pragma unroll
    for (int r = 0; r < NREP; r++) {
        int rbase = ((r << 9) | b) * CAP_R;
        int c = cnts[r], o = offs[r];
        for (int i = t; i < c; i += 512) {
            uint_t e = __builtin_nontemporal_load(&ebuf[rbase + i]);
            stage[o + i] = e;
            atomicAdd(&hist[e >> 24], 1);
        }
    }
    __syncthreads();
    int deg = 0;
    if (t < 256) { deg = hist[t]; scan[t] = deg; }
    __syncthreads();
    for (int off = 1; off < 256; off <<= 1) {
        int u = (t < 256 && t >= off) ? scan[t - off] : 0;
        __syncthreads();
        if (t < 256) scan[t] += u;
        __syncthreads();
    }
    if (t < 256) {
        int ex = scan[t] - deg;
        cur[t] = ex;
        int node = nodebase + t;
        if (node < n) {
            rowptr[node] = lo + ex;
            rowend[node] = lo + ex + deg;
            dinv[node] = rsqrtf((float)deg + 1.0f);
        }
    }
    __syncthreads();
    // scatter into this bucket's own csr region
    for (int i = t; i < tot; i += 512) {
        uint_t e = stage[i];
        int p = atomicAdd(&cur[e >> 24], 1);
        csr[lo + p] = (int)(e & 0xFFFFFFu);
    }
}

// ---------------- tiled GEMM (vector-ALU f32, register blocking) ------------
// 64 rows x H cols per block, 256 threads, 4-row x COLV thread tile, XsT
// stride 68 (17x16B) -> b128 reads; k-chunk 32 -> LDS 16.9KB -> 8 blocks/CU
// x 4 waves = 32 waves/CU. kc loop ROLLED with register double-buffer.
template<int K, int H, bool SCALE, bool BIAS, bool OBF16>
__global__ __launch_bounds__(256) void k_gemm_t(
        const float* __restrict__ X, const float* __restrict__ W,
        const float* __restrict__ bias, const float* __restrict__ dinv,
        void* __restrict__ Yv, int n) {
    constexpr int COLV = H / 16;
    constexpr int KCH = 32;             // k-chunk
    constexpr int WPT = KCH * H / 256;  // W floats per thread per chunk
    __shared__ float Ws[KCH * H];
    __shared__ float XsT[KCH][68];
    int tid = threadIdx.x;
    int tr = tid >> 4;                  // 0..15 (row group of 4)
    int tc = tid & 15;                  // 0..15 (col group of COLV)
    int rowBase = blockIdx.x * 64;
    float acc[4][COLV];
    #pragma unroll
    for (int i = 0; i < 4; i++)
        #pragma unroll
        for (int c = 0; c < COLV; c++) acc[i][c] = 0.f;

    float4 xp[2];
    float wp[WPT];
    #pragma unroll
    for (int j = 0; j < 2; j++) {
        int flat = tid + j * 256;        // 0..511
        int row = flat >> 3, kv = flat & 7;
        int gr = rowBase + row;
        xp[j] = make_float4(0.f, 0.f, 0.f, 0.f);
        if (gr < n) xp[j] = *reinterpret_cast<const float4*>(X + (size_t)gr * K + kv * 4);
    }
    #pragma unroll
    for (int j = 0; j < WPT; j++) wp[j] = W[tid + j * 256];

    #pragma unroll 1
    for (int kc = 0; kc < K; kc += KCH) {
        __syncthreads();                 // LDS free (prev compute done)
        #pragma unroll
        for (int j = 0; j < WPT; j++) Ws[tid + j * 256] = wp[j];
        #pragma unroll
        for (int j = 0; j < 2; j++) {
            int flat = tid + j * 256;
            int row = flat >> 3, kv = flat & 7;
            XsT[kv * 4 + 0][row] = xp[j].x;
            XsT[kv * 4 + 1][row] = xp[j].y;
            XsT[kv * 4 + 2][row] = xp[j].z;
            XsT[kv * 4 + 3][row] = xp[j].w;
        }
        __syncthreads();                 // LDS ready
        if (kc + KCH < K) {              // prefetch next chunk (overlaps FMAs)
            #pragma unroll
            for (int j = 0; j < 2; j++) {
                int flat = tid + j * 256;
                int row = flat >> 3, kv = flat & 7;
                int gr = rowBase + row;
                xp[j] = make_float4(0.f, 0.f, 0.f, 0.f);
                if (gr < n)
                    xp[j] = *reinterpret_cast<const float4*>(X + (size_t)gr * K + kc + KCH + kv * 4);
            }
            #pragma unroll
            for (int j = 0; j < WPT; j++) wp[j] = W[(kc + KCH) * H + tid + j * 256];
        }
        #pragma unroll
        for (int k = 0; k < KCH; k++) {
            float4 av = *reinterpret_cast<const float4*>(&XsT[k][tr * 4]);
            float avv[4] = {av.x, av.y, av.z, av.w};
            float bvv[COLV];
            if constexpr (COLV == 4) {
                float4 bv = *reinterpret_cast<const float4*>(&Ws[k * H + tc * 4]);
                bvv[0] = bv.x; bvv[1] = bv.y; bvv[2] = bv.z; bvv[3] = bv.w;
            } else {
                float2 bv = *reinterpret_cast<const float2*>(&Ws[k * H + tc * 2]);
                bvv[0] = bv.x; bvv[1] = bv.y;
            }
            #pragma unroll
            for (int i = 0; i < 4; i++)
                #pragma unroll
                for (int c = 0; c < COLV; c++)
                    acc[i][c] = fmaf(avv[i], bvv[c], acc[i][c]);
        }
    }
    #pragma unroll
    for (int i = 0; i < 4; i++) {
        int row = rowBase + tr * 4 + i;
        if (row >= n) continue;
        float s = SCALE ? dinv[row] : 1.f;
        float v[COLV];
        #pragma unroll
        for (int c = 0; c < COLV; c++) {
            float t2 = acc[i][c];
            if (SCALE) t2 *= s;
            if (BIAS)  t2 += bias[tc * COLV + c];
            v[c] = t2;
        }
        if (OBF16) {
            ushort_t* Y = (ushort_t*)Yv;
            ushort4 pk;
            pk.x = f2bf(v[0]); pk.y = f2bf(v[1]);
            pk.z = f2bf(v[2]); pk.w = f2bf(v[3]);
            *reinterpret_cast<ushort4*>(Y + (size_t)row * H + tc * COLV) = pk;
        } else {
            float* Y = (float*)Yv;
            float* yp = Y + (size_t)row * H + tc * COLV;
            if (COLV == 4)      *reinterpret_cast<float4*>(yp) = make_float4(v[0], v[1], v[2], v[3]);
            else                *reinterpret_cast<float2*>(yp) = make_float2(v[0], v[1]);
        }
    }
}

// ---------------- Aggregation: 8 edges per wave-gather (oct layout) ----------
__global__ void k_agg_bf(const int* __restrict__ rowptr, const int* __restrict__ rowend,
                         const int* __restrict__ csr, const uint_t* __restrict__ ytab,
                         const float* __restrict__ dinv, const float* __restrict__ bias,
                         float* __restrict__ out, int n) {
    int wave = (int)((blockIdx.x * (size_t)blockDim.x + threadIdx.x) >> 6);
    int lane = threadIdx.x & 63;
    if (wave >= n) return;
    int node = wave;
    int o  = lane >> 3;      // 0..7: edge slot within group of 8
    uint_t fpo = (uint_t)(lane & 7) << 4;   // byte offset of uint4 within row
    const char* yb = (const char*)ytab + fpo;   // pre-offset base (saves a VALU add per gather)
    v2f a0 = {0.f, 0.f}, a1 = {0.f, 0.f}, a2 = {0.f, 0.f}, a3 = {0.f, 0.f};
    v2f b0 = {0.f, 0.f}, b1 = {0.f, 0.f}, b2 = {0.f, 0.f}, b3 = {0.f, 0.f};
    int s = rowptr[node], e = rowend[node];
    for (int base = s; base < e; base += 64) {
        int rem = e - base; int cnt = rem > 64 ? 64 : rem;
        int idx = (base + lane < e) ? __builtin_nontemporal_load(&csr[base + lane]) : 0;
        int j = 0;
        for (; j + 32 <= cnt; j += 32) {
            uint_t s0 = (uint_t)__shfl(idx, j + o)      << 7;
            uint_t s1 = (uint_t)__shfl(idx, j + 8 + o)  << 7;
            uint_t s2 = (uint_t)__shfl(idx, j + 16 + o) << 7;
            uint_t s3 = (uint_t)__shfl(idx, j + 24 + o) << 7;
            uint4 u0 = *reinterpret_cast<const uint4*>(yb + s0);
            uint4 u1 = *reinterpret_cast<const uint4*>(yb + s1);
            uint4 u2 = *reinterpret_cast<const uint4*>(yb + s2);
            uint4 u3 = *reinterpret_cast<const uint4*>(yb + s3);
            a0 += unpk(u0.x); a1 += unpk(u0.y); a2 += unpk(u0.z); a3 += unpk(u0.w);
            b0 += unpk(u1.x); b1 += unpk(u1.y); b2 += unpk(u1.z); b3 += unpk(u1.w);
            a0 += unpk(u2.x); a1 += unpk(u2.y); a2 += unpk(u2.z); a3 += unpk(u2.w);
            b0 += unpk(u3.x); b1 += unpk(u3.y); b2 += unpk(u3.z); b3 += unpk(u3.w);
        }
        for (; j + 16 <= cnt; j += 16) {
            uint_t s0 = (uint_t)__shfl(idx, j + o)     << 7;
            uint_t s1 = (uint_t)__shfl(idx, j + 8 + o) << 7;
            uint4 u0 = *reinterpret_cast<const uint4*>(yb + s0);
            uint4 u1 = *reinterpret_cast<const uint4*>(yb + s1);
            a0 += unpk(u0.x); a1 += unpk(u0.y); a2 += unpk(u0.z); a3 += unpk(u0.w);
            b0 += unpk(u1.x); b1 += unpk(u1.y); b2 += unpk(u1.z); b3 += unpk(u1.w);
        }
        for (; j + 8 <= cnt; j += 8) {
            uint_t s0 = (uint_t)__shfl(idx, j + o) << 7;
            uint4 u0 = *reinterpret_cast<const uint4*>(yb + s0);
            a0 += unpk(u0.x); a1 += unpk(u0.y); a2 += unpk(u0.z); a3 += unpk(u0.w);
        }
        if (j < cnt) {
            int r2 = cnt - j;                    // 1..7 tail edges
            uint_t s0 = (uint_t)__shfl(idx, j + (o < r2 ? o : 0)) << 7;
            if (o < r2) {
                uint4 u0 = *reinterpret_cast<const uint4*>(yb + s0);
                a0 += unpk(u0.x); a1 += unpk(u0.y); a2 += unpk(u0.z); a3 += unpk(u0.w);
            }
        }
    }
    a0 += b0; a1 += b1; a2 += b2; a3 += b3;
    float f0 = a0.x, f1 = a0.y, f2 = a1.x, f3 = a1.y;
    float f4 = a2.x, f5 = a2.y, f6 = a3.x, f7 = a3.y;
    f0 += __shfl_xor(f0, 8); f0 += __shfl_xor(f0, 16); f0 += __shfl_xor(f0, 32);
    f1 += __shfl_xor(f1, 8); f1 += __shfl_xor(f1, 16); f1 += __shfl_xor(f1, 32);
    f2 += __shfl_xor(f2, 8); f2 += __shfl_xor(f2, 16); f2 += __shfl_xor(f2, 32);
    f3 += __shfl_xor(f3, 8); f3 += __shfl_xor(f3, 16); f3 += __shfl_xor(f3, 32);
    f4 += __shfl_xor(f4, 8); f4 += __shfl_xor(f4, 16); f4 += __shfl_xor(f4, 32);
    f5 += __shfl_xor(f5, 8); f5 += __shfl_xor(f5, 16); f5 += __shfl_xor(f5, 32);
    f6 += __shfl_xor(f6, 8); f6 += __shfl_xor(f6, 16); f6 += __shfl_xor(f6, 32);
    f7 += __shfl_xor(f7, 8); f7 += __shfl_xor(f7, 16); f7 += __shfl_xor(f7, 32);
    if (o == 0) {
        uint4 su = *reinterpret_cast<const uint4*>(yb + ((uint_t)node << 7));  // self-loop
        v2f s0 = unpk(su.x), s1 = unpk(su.y), s2 = unpk(su.z), s3 = unpk(su.w);
        f0 += s0.x; f1 += s0.y; f2 += s1.x; f3 += s1.y;
        f4 += s2.x; f5 += s2.y; f6 += s3.x; f7 += s3.y;
        float di = dinv[node];
        int fp8 = (lane & 7) << 3;
        float4 c0 = *reinterpret_cast<const float4*>(bias + fp8);
        float4 c1 = *reinterpret_cast<const float4*>(bias + fp8 + 4);
        float4 v0, v1;
        v0.x = fmaxf(fmaf(di, f0, c0.x), 0.f);
        v0.y = fmaxf(fmaf(di, f1, c0.y), 0.f);
        v0.z = fmaxf(fmaf(di, f2, c0.z), 0.f);
        v0.w = fmaxf(fmaf(di, f3, c0.w), 0.f);
        v1.x = fmaxf(fmaf(di, f4, c1.x), 0.f);
        v1.y = fmaxf(fmaf(di, f5, c1.y), 0.f);
        v1.z = fmaxf(fmaf(di, f6, c1.z), 0.f);
        v1.w = fmaxf(fmaf(di, f7, c1.w), 0.f);
        float* op = out + (size_t)node * 64 + fp8;
        *reinterpret_cast<float4*>(op) = v0;
        *reinterpret_cast<float4*>(op + 4) = v1;
    }
}

// ---------------- launch ----------------
extern "C" void kernel_launch(void* const* d_in, const int* in_sizes, int n_in,
                              void* d_out, int out_size, void* d_ws, size_t ws_size,
                              hipStream_t stream) {
    const float* x  = (const float*)d_in[0];
    const int*   ei = (const int*)d_in[1];
    const float* W1 = (const float*)d_in[2];
    const float* b1 = (const float*)d_in[3];
    const float* W2 = (const float*)d_in[4];
    const float* b2 = (const float*)d_in[5];
    const float* Wl = (const float*)d_in[6];
    const float* bl = (const float*)d_in[7];
    float* out = (float*)d_out;

    const int n = in_sizes[0] / 128;     // 100000
    const int E = in_sizes[1] / 2;       // 3200000
    const int* src = ei;
    const int* dst = ei + E;
    const int nbuk = (n + 255) >> 8;     // 391

    char* p = (char*)d_ws;
    auto alloc = [&](size_t bytes) { char* r = p; p += (bytes + 255) & ~(size_t)255; return r; };
    float* dinv   = (float*)alloc((size_t)n * 4);
    int*   bcur   = (int*)  alloc(NREP * MAXBUK * 4);
    int*   rowptr = (int*)  alloc((size_t)n * 4);
    int*   rowend = (int*)  alloc((size_t)n * 4);
    int*   csr    = (int*)  alloc((size_t)MAXBUK * CAPB * 4 + 256);
    ushort_t* bufY = (ushort_t*)alloc((size_t)n * 64 * 2);  // bf16 msg table L1
    float* bufA   = (float*)alloc((size_t)n * 64 * 4);      // f32 activations
    ushort_t* bufB = (ushort_t*)alloc((size_t)n * 64 * 2);  // bf16 msg table L2
    (void)ws_size;

    // ebuf (NREP*MAXBUK*CAP_R*4 = 25.2MB) aliases bufA (25.6MB): ebuf is dead
    // after k_csr2, before agg1 writes bufA.
    uint_t* ebuf = (uint_t*)bufA;

    hipMemsetAsync(bcur, 0, NREP * MAXBUK * 4, stream);   // counts, not cursors
    k_part3<<<(E + PTILE - 1) / PTILE, 512, 0, stream>>>(src, dst, bcur, ebuf, E);
    k_csr2<<<nbuk, 512, 0, stream>>>(ebuf, bcur, rowptr, rowend, dinv, csr, n);

    const int GB = (n + 63) / 64;        // 1563 blocks, 256 threads
    const int AB = (n + 3) / 4;

    // layer 1: y = dinv ⊙ (x @ W1) [bf16]; h1 = relu(dinv*agg + b1) [f32]
    k_gemm_t<128, 64, true, false, true><<<GB, 256, 0, stream>>>(x, W1, nullptr, dinv, bufY, n);
    k_agg_bf<<<AB, 256, 0, stream>>>(rowptr, rowend, csr, (const uint_t*)bufY, dinv, b1, bufA, n);

    // layer 2
    k_gemm_t<64, 64, true, false, true><<<GB, 256, 0, stream>>>(bufA, W2, nullptr, dinv, bufB, n);
    k_agg_bf<<<AB, 256, 0, stream>>>(rowptr, rowend, csr, (const uint_t*)bufB, dinv, b2, bufA, n);

    // head: out = h2 @ Wl + bl (f32)
    k_gemm_t<64, 32, false, true, false><<<GB, 256, 0, stream>>>(bufA, Wl, bl, nullptr, out, n);
}